// Round 19
// baseline (323.236 us; speedup 1.0000x reference)
//
#include <hip/hip_runtime.h>
#include <hip/hip_bf16.h>

typedef float f4 __attribute__((ext_vector_type(4)));
typedef short bh8 __attribute__((ext_vector_type(8)));   // 8 bf16 (4 VGPRs)

#define EMB 128
#define HID 512

__device__ __forceinline__ float bfbits2f(unsigned int lo16) {
    unsigned int u = lo16 << 16;
    return __builtin_bit_cast(float, u);
}
__device__ __forceinline__ short f2bf(float f) {
    __hip_bfloat16 h = __float2bfloat16(f);
    return __builtin_bit_cast(short, h);
}
// fast GELU: x*sigmoid(1.5957691x + 0.0713548x^3); |err vs erf-GELU| <~1e-3,
// below the bf16 rounding applied to h.
__device__ __forceinline__ float gelu_fast(float x) {
    float x3 = x * x * x;
    float y = 1.5957691216f * x + 0.0713548163f * x3;
    return x / (1.0f + __expf(-y));
}

// ---------------------------------------------------------------------------
// Counting sort of edges by destination A (round-9 proven path).
// ---------------------------------------------------------------------------
__global__ void hist_kernel(const int* __restrict__ edge, unsigned* __restrict__ cnt, int E) {
    int stride = gridDim.x * blockDim.x;
    for (int e = blockIdx.x * blockDim.x + threadIdx.x; e < E; e += stride)
        atomicAdd(&cnt[edge[e]], 1u);
}

__global__ void scan_blocks(const unsigned* __restrict__ cnt, int* __restrict__ off,
                            int* __restrict__ bsum, int n) {
    __shared__ int ls[256];
    int tid = threadIdx.x;
    int base = blockIdx.x * 1024 + tid * 4;
    int v0 = 0, v1 = 0, v2 = 0, v3 = 0;
    if (base + 0 < n) v0 = (int)cnt[base + 0];
    if (base + 1 < n) v1 = (int)cnt[base + 1];
    if (base + 2 < n) v2 = (int)cnt[base + 2];
    if (base + 3 < n) v3 = (int)cnt[base + 3];
    int s = v0 + v1 + v2 + v3;
    ls[tid] = s;
    __syncthreads();
    for (int d = 1; d < 256; d <<= 1) {
        int t = (tid >= d) ? ls[tid - d] : 0;
        __syncthreads();
        ls[tid] += t;
        __syncthreads();
    }
    int incl = ls[tid];
    int run = incl - s;
    if (tid == 255) bsum[blockIdx.x] = incl;
    if (base + 0 < n) { off[base + 0] = run; run += v0; }
    if (base + 1 < n) { off[base + 1] = run; run += v1; }
    if (base + 2 < n) { off[base + 2] = run; run += v2; }
    if (base + 3 < n) { off[base + 3] = run; }
}

__global__ void scan_bsums(int* __restrict__ bsum, int nb) {
    int lane = threadIdx.x & 63;
    int x = (lane < nb) ? bsum[lane] : 0;
    int orig = x;
#pragma unroll
    for (int o = 1; o < 64; o <<= 1) {
        int t = __shfl_up(x, o, 64);
        if (lane >= o) x += t;
    }
    if (lane < nb) bsum[lane] = x - orig;
}

__global__ void scan_apply(const unsigned* __restrict__ cnt, const int* __restrict__ bsum,
                           int* __restrict__ off, int* __restrict__ offw,
                           float* __restrict__ cntf, int n) {
    int base = blockIdx.x * 1024 + threadIdx.x * 4;
    int add = bsum[blockIdx.x];
#pragma unroll
    for (int i = 0; i < 4; ++i) {
        int idx = base + i;
        if (idx < n) {
            int o = off[idx] + add;
            off[idx] = o;
            offw[idx] = o;
            cntf[idx] = (float)cnt[idx];
        }
    }
}

__global__ void place_kernel(const int* __restrict__ edge, int* __restrict__ offw,
                             int* __restrict__ sortedB, int E) {
    int stride = gridDim.x * blockDim.x;
    for (int e = blockIdx.x * blockDim.x + threadIdx.x; e < E; e += stride) {
        int a = edge[e];
        int pos = atomicAdd(&offw[a], 1);
        sortedB[pos] = edge[E + e];
    }
}

// ---------------------------------------------------------------------------
// Merged weight prep: all 6 transposes + bias concat in ONE launch.
// ---------------------------------------------------------------------------
__global__ void prep_all(const float* __restrict__ wq, const float* __restrict__ wk,
                         const float* __restrict__ wv, const float* __restrict__ wo,
                         const float* __restrict__ w1, const float* __restrict__ w2,
                         const float* __restrict__ bq, const float* __restrict__ bk,
                         const float* __restrict__ bv,
                         short* __restrict__ wqkvT, short* __restrict__ woT,
                         short* __restrict__ w1T, short* __restrict__ w2T,
                         float* __restrict__ bqkv) {
    int id = blockIdx.x * blockDim.x + threadIdx.x;
    if (id < 16384) {
        int k = id >> 7, c = id & 127;
        wqkvT[c * 128 + k] = f2bf(wq[id]);
    } else if (id < 32768) {
        int t = id - 16384; int k = t >> 7, c = t & 127;
        wqkvT[(128 + c) * 128 + k] = f2bf(wk[t]);
    } else if (id < 49152) {
        int t = id - 32768; int k = t >> 7, c = t & 127;
        wqkvT[(256 + c) * 128 + k] = f2bf(wv[t]);
    } else if (id < 65536) {
        int t = id - 49152; int k = t >> 7, c = t & 127;
        woT[c * 128 + k] = f2bf(wo[t]);
    } else if (id < 131072) {
        int t = id - 65536; int k = t >> 9, c = t & 511;
        w1T[c * 128 + k] = f2bf(w1[t]);
    } else if (id < 196608) {
        int t = id - 131072; int k = t >> 7, c = t & 127;
        w2T[c * 512 + k] = f2bf(w2[t]);
    }
    if (id < 128) {
        bqkv[id] = bq[id];
        bqkv[128 + id] = bk[id];
        bqkv[256 + id] = bv[id];
    }
}

// ---------------------------------------------------------------------------
// Fragment loader for one k-step (32 cols): 4 A frags + 4 B frags.
// ---------------------------------------------------------------------------
template<int KT, bool IN_BF16>
__device__ __forceinline__ void ld_ab(bh8 (&av)[4], bh8 (&bv)[4],
                                      const float* __restrict__ Xf, const short* __restrict__ Xb,
                                      const int (&rowA)[4], const short* __restrict__ Wt,
                                      int C0, int l15, int kbase) {
#pragma unroll
    for (int rf = 0; rf < 4; ++rf) {
        if constexpr (IN_BF16) {
            av[rf] = *(const bh8*)(Xb + (size_t)rowA[rf] * KT + kbase);
        } else {
            f4 lo = *(const f4*)(Xf + (size_t)rowA[rf] * KT + kbase);
            f4 hi = *(const f4*)(Xf + (size_t)rowA[rf] * KT + kbase + 4);
            bh8 t;
            t[0] = f2bf(lo[0]); t[1] = f2bf(lo[1]); t[2] = f2bf(lo[2]); t[3] = f2bf(lo[3]);
            t[4] = f2bf(hi[0]); t[5] = f2bf(hi[1]); t[6] = f2bf(hi[2]); t[7] = f2bf(hi[3]);
            av[rf] = t;
        }
    }
#pragma unroll
    for (int cf = 0; cf < 4; ++cf)
        bv[cf] = *(const bh8*)(Wt + (size_t)(C0 + cf * 16 + l15) * KT + kbase);
}

__device__ __forceinline__ void mm16(f4 (&acc)[4][4], const bh8 (&av)[4], const bh8 (&bv)[4]) {
#pragma unroll
    for (int rf = 0; rf < 4; ++rf)
#pragma unroll
        for (int cf = 0; cf < 4; ++cf)
            acc[rf][cf] = __builtin_amdgcn_mfma_f32_16x16x32_bf16(av[rf], bv[cf], acc[rf][cf], 0, 0, 0);
}

__device__ __forceinline__ void mm8(f4 (&acc)[2][4], const bh8 (&av)[2], const bh8 (&bv)[4]) {
#pragma unroll
    for (int rf = 0; rf < 2; ++rf)
#pragma unroll
        for (int cf = 0; cf < 4; ++cf)
            acc[rf][cf] = __builtin_amdgcn_mfma_f32_16x16x32_bf16(av[rf], bv[cf], acc[rf][cf], 0, 0, 0);
}

// ---------------------------------------------------------------------------
// MFMA GEMM (qkv / wo): 256 threads = 2x2 waves; 128x128 per block.
// 2-deep ping-pong K-pipeline. XCD-aware panel placement.
// ---------------------------------------------------------------------------
#define CSTRIDE 136   // shorts; 272B row stride: 16B-aligned, breaks kg bank aliasing

template<int KT, bool IN_BF16, bool GELU, bool OUT_BF16, bool RESID, bool RBF16, bool STATS>
__global__ __launch_bounds__(256, 2) void mfma_gemm(
    const void* __restrict__ Xv, const short* __restrict__ Wt, const float* __restrict__ bias,
    const void* __restrict__ resid,
    void* __restrict__ outv, float* __restrict__ slots, int n, int OC, int ncolb, int nrb)
{
    int bx, by;
    if (ncolb == 1) {
        bx = blockIdx.x; by = 0;
    } else {
        int q = blockIdx.x >> 3;
        by = q % ncolb;
        bx = (q / ncolb) * 8 + (blockIdx.x & 7);
        if (bx >= nrb) return;
    }
    const int lane = threadIdx.x & 63;
    const int w = threadIdx.x >> 6;
    const int wr = w >> 1, wc = w & 1;
    const int R0 = bx * 128 + wr * 64;
    const int C0 = by * 128 + wc * 64;
    const int l15 = lane & 15;
    const int kg = lane >> 4;

    const float* Xf = (const float*)Xv;
    const short* Xb = (const short*)Xv;

    int rowA[4];
#pragma unroll
    for (int rf = 0; rf < 4; ++rf) rowA[rf] = min(R0 + rf * 16 + l15, n - 1);

    f4 acc[4][4];
#pragma unroll
    for (int rf = 0; rf < 4; ++rf)
#pragma unroll
        for (int cf = 0; cf < 4; ++cf) acc[rf][cf] = 0.f;

    constexpr int NT = KT / 32;
    bh8 aA[4], bA[4], aB[4], bB[4];

    ld_ab<KT, IN_BF16>(aA, bA, Xf, Xb, rowA, Wt, C0, l15, kg * 8);
#pragma unroll
    for (int t = 0; t < NT; t += 2) {
        ld_ab<KT, IN_BF16>(aB, bB, Xf, Xb, rowA, Wt, C0, l15, (t + 1) * 32 + kg * 8);
        mm16(acc, aA, bA);
        if (t + 2 < NT)
            ld_ab<KT, IN_BF16>(aA, bA, Xf, Xb, rowA, Wt, C0, l15, (t + 2) * 32 + kg * 8);
        mm16(acc, aB, bB);
    }

    if constexpr (OUT_BF16) {
        extern __shared__ short cs[];
        const int lrb = wr * 64;
        const int lcb = wc * 64;
#pragma unroll
        for (int cf = 0; cf < 4; ++cf) {
            const float bcol = bias[C0 + cf * 16 + l15];
#pragma unroll
            for (int rf = 0; rf < 4; ++rf) {
#pragma unroll
                for (int i = 0; i < 4; ++i) {
                    float val = acc[rf][cf][i] + bcol;
                    if constexpr (GELU) val = gelu_fast(val);
                    cs[(lrb + rf * 16 + kg * 4 + i) * CSTRIDE + lcb + cf * 16 + l15] = f2bf(val);
                }
            }
        }
        __syncthreads();
        const int tc = threadIdx.x & 15;
        const int tr = threadIdx.x >> 4;
        const int gcb = by * 128;
#pragma unroll
        for (int r = 0; r < 8; ++r) {
            int lrow = tr + r * 16;
            int grow = bx * 128 + lrow;
            if (grow < n) {
                bh8 v = *(bh8*)(cs + lrow * CSTRIDE + tc * 8);
                *(bh8*)((short*)outv + (size_t)grow * OC + gcb + tc * 8) = v;
            }
        }
    } else {
#pragma unroll
        for (int cf = 0; cf < 4; ++cf) {
            const int col = C0 + cf * 16 + l15;
            const float bcol = bias[col];
#pragma unroll
            for (int rf = 0; rf < 4; ++rf) {
                float s = 0.f, q = 0.f;
#pragma unroll
                for (int i = 0; i < 4; ++i) {
                    const int row = R0 + rf * 16 + kg * 4 + i;
                    if (row < n) {
                        float val = acc[rf][cf][i] + bcol;
                        if constexpr (RESID) {
                            float rv;
                            if constexpr (RBF16)
                                rv = bfbits2f((unsigned short)((const short*)resid)[(size_t)row * EMB + col]);
                            else
                                rv = ((const float*)resid)[(size_t)row * EMB + col];
                            val += rv;
                        }
                        if constexpr (GELU) val = gelu_fast(val);
                        if constexpr (STATS) { s += val; q += val * val; }
                        ((float*)outv)[(size_t)row * OC + col] = val;
                    }
                }
                if constexpr (STATS) {
                    s += __shfl_xor(s, 16, 64); s += __shfl_xor(s, 32, 64);
                    q += __shfl_xor(q, 16, 64); q += __shfl_xor(q, 32, 64);
                    if (kg == 0) {
                        float* sl = slots + (size_t)(bx & 63) * 256;
                        unsafeAtomicAdd(&sl[col], s);
                        unsafeAtomicAdd(&sl[128 + col], q);
                    }
                }
            }
        }
    }
}

// ---------------------------------------------------------------------------
// FUSED FFN v4: 64-row blocks (782 -> ~3 blocks/CU, 2x occupancy vs v2's 391).
// 2x2 waves of 32 rows x 64 cols. Same two-barrier chunk structure as the
// proven round-16 version (FC2 LDS reads are cross-wave-after-barrier; the
// same-wave ds_write->ds_read chain of round 17 is avoided).
// y2 = gelu(xn1@w1+b1)@w2 + b2 + xn1, fused BN2 stats.
// ---------------------------------------------------------------------------
__global__ __launch_bounds__(256, 3) void ffn_fused(
    const short* __restrict__ xn1, const short* __restrict__ w1T, const float* __restrict__ b1,
    const short* __restrict__ w2T, const float* __restrict__ b2,
    float* __restrict__ y2, float* __restrict__ slots, int n)
{
    extern __shared__ short hs[];   // [64][CSTRIDE] bf16
    const int bx = blockIdx.x;
    const int lane = threadIdx.x & 63;
    const int w = threadIdx.x >> 6;
    const int wr = w >> 1, wc = w & 1;
    const int R0 = bx * 64 + wr * 32;
    const int l15 = lane & 15;
    const int kg = lane >> 4;

    int rowA[2];
#pragma unroll
    for (int rf = 0; rf < 2; ++rf) rowA[rf] = min(R0 + rf * 16 + l15, n - 1);

    // hoisted xn1 A-fragments: same for every h-chunk (8 bh8 = 32 VGPRs)
    bh8 aF0[2], aF1[2], aF2[2], aF3[2];
#pragma unroll
    for (int rf = 0; rf < 2; ++rf) {
        const short* p = xn1 + (size_t)rowA[rf] * EMB + kg * 8;
        aF0[rf] = *(const bh8*)(p);
        aF1[rf] = *(const bh8*)(p + 32);
        aF2[rf] = *(const bh8*)(p + 64);
        aF3[rf] = *(const bh8*)(p + 96);
    }

    f4 acc2[2][4];
#pragma unroll
    for (int rf = 0; rf < 2; ++rf)
#pragma unroll
        for (int cf = 0; cf < 4; ++cf) acc2[rf][cf] = 0.f;

    const int lrb = wr * 32;
    const int lcb = wc * 64;

    for (int c = 0; c < 4; ++c) {
        // ---- FC1 chunk: acc1 = xn1(32 rows) @ w1T[cols c*128+wc*64 .. +63] ----
        f4 acc1[2][4];
#pragma unroll
        for (int rf = 0; rf < 2; ++rf)
#pragma unroll
            for (int cf = 0; cf < 4; ++cf) acc1[rf][cf] = 0.f;

        bh8 bP[4], bQ[4];
        auto ldB1 = [&](bh8 (&dst)[4], int ks) {
#pragma unroll
            for (int cf = 0; cf < 4; ++cf) {
                int col = c * 128 + wc * 64 + cf * 16 + l15;
                dst[cf] = *(const bh8*)(w1T + (size_t)col * EMB + ks * 32 + kg * 8);
            }
        };
        ldB1(bP, 0);
        ldB1(bQ, 1);
        mm8(acc1, aF0, bP);
        ldB1(bP, 2);
        mm8(acc1, aF1, bQ);
        ldB1(bQ, 3);
        mm8(acc1, aF2, bP);
        mm8(acc1, aF3, bQ);

        // ---- fast GELU -> LDS tile ----
        __syncthreads();   // protect previous chunk's LDS reads
#pragma unroll
        for (int cf = 0; cf < 4; ++cf) {
            const float bcol = b1[c * 128 + wc * 64 + cf * 16 + l15];
#pragma unroll
            for (int rf = 0; rf < 2; ++rf) {
#pragma unroll
                for (int i = 0; i < 4; ++i) {
                    float val = gelu_fast(acc1[rf][cf][i] + bcol);
                    hs[(lrb + rf * 16 + kg * 4 + i) * CSTRIDE + lcb + cf * 16 + l15] = f2bf(val);
                }
            }
        }
        __syncthreads();

        // ---- FC2 partial: acc2 += h_chunk(32 rows x 128) @ w2T[:, c*128..] ----
        bh8 aP[2], aQ[2];
        auto ldA2 = [&](bh8 (&dst)[2], int ks) {
#pragma unroll
            for (int rf = 0; rf < 2; ++rf)
                dst[rf] = *(const bh8*)(hs + (lrb + rf * 16 + l15) * CSTRIDE + ks * 32 + kg * 8);
        };
        auto ldB2 = [&](bh8 (&dst)[4], int ks) {
#pragma unroll
            for (int cf = 0; cf < 4; ++cf) {
                int col = wc * 64 + cf * 16 + l15;
                dst[cf] = *(const bh8*)(w2T + (size_t)col * HID + c * 128 + ks * 32 + kg * 8);
            }
        };
        ldA2(aP, 0); ldB2(bP, 0);
        ldA2(aQ, 1); ldB2(bQ, 1);
        mm8(acc2, aP, bP);
        ldA2(aP, 2); ldB2(bP, 2);
        mm8(acc2, aQ, bQ);
        ldA2(aQ, 3); ldB2(bQ, 3);
        mm8(acc2, aP, bP);
        mm8(acc2, aQ, bQ);
    }

    // ---- epilogue: y2 = acc2 + b2 + xn1 (bf16 resid), fused BN2 stats ----
    const int C0 = wc * 64;
#pragma unroll
    for (int cf = 0; cf < 4; ++cf) {
        const int col = C0 + cf * 16 + l15;
        const float bcol = b2[col];
#pragma unroll
        for (int rf = 0; rf < 2; ++rf) {
            float s = 0.f, q = 0.f;
#pragma unroll
            for (int i = 0; i < 4; ++i) {
                const int row = R0 + rf * 16 + kg * 4 + i;
                if (row < n) {
                    float val = acc2[rf][cf][i] + bcol;
                    val += bfbits2f((unsigned short)xn1[(size_t)row * EMB + col]);
                    s += val; q += val * val;
                    y2[(size_t)row * EMB + col] = val;
                }
            }
            s += __shfl_xor(s, 16, 64); s += __shfl_xor(s, 32, 64);
            q += __shfl_xor(q, 16, 64); q += __shfl_xor(q, 32, 64);
            if (kg == 0) {
                float* sl = slots + (size_t)(bx & 63) * 256;
                unsafeAtomicAdd(&sl[col], s);
                unsafeAtomicAdd(&sl[128 + col], q);
            }
        }
    }
}

// ---------------------------------------------------------------------------
// FUSED gather+attention (round-14 vector-load version).
// ---------------------------------------------------------------------------
__global__ void gather_attn_kernel(const short* __restrict__ qkv, const int* __restrict__ off,
                                   const unsigned* __restrict__ cnt, const int* __restrict__ sortedB,
                                   const float* __restrict__ cntf, short* __restrict__ attno, int n) {
    int wid = (int)((blockIdx.x * blockDim.x + threadIdx.x) >> 6);
    int lane = threadIdx.x & 63;
    int nw = (gridDim.x * blockDim.x) >> 6;
    const int l15 = lane & 15;
    const int grp = lane >> 4;
    const int h = lane >> 3, g = lane & 7;
    for (int node = wid; node < n; node += nw) {
        int start = off[node];
        int deg = (int)cnt[node];
        float a[8];
#pragma unroll
        for (int i = 0; i < 8; ++i) a[i] = 0.f;
        for (int j = 0; j < deg; j += 8) {
            int i0 = j + grp, i1 = j + 4 + grp;
            uint4 u0 = make_uint4(0, 0, 0, 0), u1 = make_uint4(0, 0, 0, 0);
            if (i0 < deg) {
                int b = sortedB[start + i0];
                u0 = *(const uint4*)(qkv + (size_t)b * 384 + 128 + l15 * 8);
            }
            if (i1 < deg) {
                int b = sortedB[start + i1];
                u1 = *(const uint4*)(qkv + (size_t)b * 384 + 128 + l15 * 8);
            }
            unsigned w0[4] = {u0.x, u0.y, u0.z, u0.w};
            unsigned w1[4] = {u1.x, u1.y, u1.z, u1.w};
#pragma unroll
            for (int i = 0; i < 4; ++i) {
                a[2 * i]     += bfbits2f(w0[i] & 0xffffu) + bfbits2f(w1[i] & 0xffffu);
                a[2 * i + 1] += bfbits2f(w0[i] >> 16)     + bfbits2f(w1[i] >> 16);
            }
        }
#pragma unroll
        for (int i = 0; i < 8; ++i) {
            a[i] += __shfl_xor(a[i], 16, 64);
            a[i] += __shfl_xor(a[i], 32, 64);
        }

        const short* qp = qkv + (size_t)node * 384 + h * 16;
        uint4 qa = *(const uint4*)qp;
        uint4 qb = *(const uint4*)(qp + 8);
        float qv[16];
        {
            unsigned ua[4] = {qa.x, qa.y, qa.z, qa.w};
            unsigned ub[4] = {qb.x, qb.y, qb.z, qb.w};
#pragma unroll
            for (int w2 = 0; w2 < 4; ++w2) {
                qv[2 * w2]         = bfbits2f(ua[w2] & 0xffffu);
                qv[2 * w2 + 1]     = bfbits2f(ua[w2] >> 16);
                qv[8 + 2 * w2]     = bfbits2f(ub[w2] & 0xffffu);
                qv[8 + 2 * w2 + 1] = bfbits2f(ub[w2] >> 16);
            }
        }
        float s = 0.f;
#pragma unroll
        for (int i = 0; i < 8; ++i) {
            s += qv[i]     * __shfl(a[i], 2 * g, 64);
            s += qv[8 + i] * __shfl(a[i], 2 * g + 1, 64);
        }
        float c = cntf[node];
        s *= 1.0f / fmaxf(c, 1.0f);
        float m = s;
#pragma unroll
        for (int o = 1; o < 8; o <<= 1) m = fmaxf(m, __shfl_xor(m, o, 64));
        float e = __expf(s - m);
        float sum = e;
#pragma unroll
        for (int o = 1; o < 8; o <<= 1) sum += __shfl_xor(sum, o, 64);
        float p = e / sum;
        float o0 = 0.f, o1 = 0.f;
        int d0 = g * 2;
#pragma unroll
        for (int gg = 0; gg < 8; ++gg) {
            float pg = __shfl(p, h * 8 + gg, 64);
            unsigned vv = *(const unsigned*)(qkv + (size_t)node * 384 + 256 + gg * 16 + d0);
            o0 += pg * bfbits2f(vv & 0xffffu);
            o1 += pg * bfbits2f(vv >> 16);
        }
        unsigned pk = (unsigned)(unsigned short)f2bf(o0) | ((unsigned)(unsigned short)f2bf(o1) << 16);
        *(unsigned*)(attno + (size_t)node * EMB + h * 16 + d0) = pk;
    }
}

// ---------------------------------------------------------------------------
// BatchNorm helpers
// ---------------------------------------------------------------------------
__global__ void bn_finalize_slots(const float* __restrict__ slots, float* __restrict__ scsh,
                                  const float* __restrict__ g, const float* __restrict__ be, int n) {
    int c = threadIdx.x;
    float s = 0.f, q = 0.f;
    for (int i = 0; i < 64; ++i) {
        s += slots[(size_t)i * 256 + c];
        q += slots[(size_t)i * 256 + 128 + c];
    }
    float invn = 1.0f / (float)n;
    float mean = s * invn;
    float var = fmaxf(q * invn - mean * mean, 0.f);
    float sc = g[c] * rsqrtf(var + 1e-5f);
    scsh[c] = sc;
    scsh[128 + c] = be[c] - mean * sc;
}

// xn1 = bf16(bn1(y1)) : read fp32, apply scale/shift, write bf16
__global__ void apply_bn_bf16(const float* __restrict__ Y, const float* __restrict__ scsh,
                              short* __restrict__ out, size_t total8) {
    size_t stride = (size_t)gridDim.x * blockDim.x;
    for (size_t i = (size_t)blockIdx.x * blockDim.x + threadIdx.x; i < total8; i += stride) {
        size_t base = i * 8;
        f4 lo = *(const f4*)(Y + base);
        f4 hi = *(const f4*)(Y + base + 4);
        int c = (int)(base & 127);
        f4 s0 = *(const f4*)(scsh + c);
        f4 s1 = *(const f4*)(scsh + c + 4);
        f4 h0 = *(const f4*)(scsh + 128 + c);
        f4 h1 = *(const f4*)(scsh + 128 + c + 4);
        lo = lo * s0 + h0;
        hi = hi * s1 + h1;
        bh8 o;
        o[0] = f2bf(lo[0]); o[1] = f2bf(lo[1]); o[2] = f2bf(lo[2]); o[3] = f2bf(lo[3]);
        o[4] = f2bf(hi[0]); o[5] = f2bf(hi[1]); o[6] = f2bf(hi[2]); o[7] = f2bf(hi[3]);
        *(bh8*)(out + base) = o;
    }
}

__global__ void bn_apply(float* __restrict__ Y, const float* __restrict__ scsh, size_t total4) {
    size_t stride = (size_t)gridDim.x * blockDim.x;
    for (size_t i = (size_t)blockIdx.x * blockDim.x + threadIdx.x; i < total4; i += stride) {
        f4 vv = ((f4*)Y)[i];
        int c = (int)((i * 4) & 127);
#pragma unroll
        for (int j = 0; j < 4; ++j) vv[j] = vv[j] * scsh[c + j] + scsh[128 + c + j];
        ((f4*)Y)[i] = vv;
    }
}

// ---------------------------------------------------------------------------
extern "C" void kernel_launch(void* const* d_in, const int* in_sizes, int n_in,
                              void* d_out, int out_size, void* d_ws, size_t ws_size,
                              hipStream_t stream) {
    const float* x   = (const float*)d_in[0];
    const float* wq  = (const float*)d_in[1];
    const float* bq  = (const float*)d_in[2];
    const float* wk  = (const float*)d_in[3];
    const float* bk  = (const float*)d_in[4];
    const float* wv  = (const float*)d_in[5];
    const float* bv  = (const float*)d_in[6];
    const float* wo  = (const float*)d_in[7];
    const float* bo  = (const float*)d_in[8];
    const float* w1  = (const float*)d_in[9];
    const float* b1  = (const float*)d_in[10];
    const float* w2  = (const float*)d_in[11];
    const float* b2  = (const float*)d_in[12];
    const float* g1  = (const float*)d_in[13];
    const float* be1 = (const float*)d_in[14];
    const float* g2  = (const float*)d_in[15];
    const float* be2 = (const float*)d_in[16];
    const int* edge  = (const int*)d_in[17];

    int n = in_sizes[0] / EMB;      // 50000
    int E = in_sizes[17] / 2;       // 800000

    // workspace layout (float units)
    float* wsf = (float*)d_ws;
    unsigned* cnt_u = (unsigned*)wsf;                       // 65536
    float*  cntf  = wsf + 65536;                            // 65536
    int*    off   = (int*)(wsf + 2 * 65536);                // 65536
    int*    offw  = (int*)(wsf + 3 * 65536);                // 65536
    int*    bsum  = (int*)(wsf + 4 * 65536);                // 64
    int*    sortedB = (int*)(wsf + 4 * 65536 + 64);         // E
    float*  base5 = wsf + 4 * 65536 + 64 + E;
    short*  qkv   = (short*)base5;                          // n*384 bf16 = n*192 f
    short*  attno = (short*)(base5 + (size_t)n * 256);      // n*128 bf16
    float*  y1    = base5 + (size_t)n * 320;                // n*128 f
    float*  warea = y1 + (size_t)n * 128;
    short*  wqkvT = (short*)warea;                          // 384*128 bf16
    short*  woT   = wqkvT + 384 * 128;                      // 128*128
    short*  w1T   = woT + 128 * 128;                        // 512*128
    short*  w2T   = w1T + 512 * 128;                        // 128*512
    float*  bqkv  = (float*)(w2T + 128 * 512);              // 384
    float*  slots1 = bqkv + 384;                            // 64*256
    float*  slots2 = slots1 + 64 * 256;                     // 64*256
    float*  scsh1  = slots2 + 64 * 256;                     // 256
    float*  scsh2  = scsh1 + 256;                           // 256
    short*  xn1   = attno;                                  // n*128 bf16 (attno dead after wo-GEMM)
    float*  y2    = (float*)d_out;

    hipMemsetAsync(cnt_u, 0, 65536 * sizeof(unsigned), stream);
    hipMemsetAsync(slots1, 0, 2 * 64 * 256 * sizeof(float), stream);

    // edge counting sort
    int nb = (n + 1023) / 1024;  // 49
    hist_kernel<<<2048, 256, 0, stream>>>(edge, cnt_u, E);
    scan_blocks<<<nb, 256, 0, stream>>>(cnt_u, off, bsum, n);
    scan_bsums<<<1, 64, 0, stream>>>(bsum, nb);
    scan_apply<<<nb, 256, 0, stream>>>(cnt_u, bsum, off, offw, cntf, n);
    place_kernel<<<2048, 256, 0, stream>>>(edge, offw, sortedB, E);

    // merged weight prep (6 transposes + bias concat, one launch)
    prep_all<<<768, 256, 0, stream>>>(wq, wk, wv, wo, w1, w2, bq, bk, bv,
                                      wqkvT, woT, w1T, w2T, bqkv);

    int nrb = (n + 127) / 128;              // 391 row-groups
    int nrb8 = ((nrb + 7) / 8) * 8;         // 392, XCD-aligned
    const size_t CSH = 128 * CSTRIDE * sizeof(short);      // 34816 B
    const size_t CSH_FFN = 64 * CSTRIDE * sizeof(short);   // 17408 B

    // qkv = x @ [wq|wk|wv] + bqkv  (fp32 in, converted in-reg; bf16 out [n][384])
    mfma_gemm<128, false, false, true, false, false, false><<<nrb8 * 3, 256, CSH, stream>>>(
        x, wqkvT, bqkv, nullptr, qkv, nullptr, n, 384, 3, nrb);

    // fused: ksum gather (in regs, vector loads) + attention -> attno
    gather_attn_kernel<<<4096, 256, 0, stream>>>(qkv, off, cnt_u, sortedB, cntf, attno, n);

    // y1 = attno@wo + bo + x (fp32 out) + fused BN1 stats
    mfma_gemm<128, true, false, false, true, false, true><<<nrb, 256, 0, stream>>>(
        attno, woT, bo, x, y1, slots1, n, EMB, 1, nrb);

    bn_finalize_slots<<<1, 128, 0, stream>>>(slots1, scsh1, g1, be1, n);

    // xn1 = bf16(bn1(y1))  (overwrites attno region; attno is dead)
    apply_bn_bf16<<<1600, 256, 0, stream>>>(y1, scsh1, xn1, (size_t)n * EMB / 8);

    // FUSED FFN (64-row blocks): y2 = gelu(xn1@w1+b1)@w2 + b2 + xn1, + BN2 stats
    int nrb64 = (n + 63) / 64;              // 782
    ffn_fused<<<nrb64, 256, CSH_FFN, stream>>>(xn1, w1T, b1, w2T, b2, y2, slots2, n);

    bn_finalize_slots<<<1, 128, 0, stream>>>(slots2, scsh2, g2, be2, n);
    bn_apply<<<512, 256, 0, stream>>>(y2, scsh2, (size_t)n * EMB / 4);
}

// Round 20
// 304.959 us; speedup vs baseline: 1.0599x; 1.0599x over previous
//
#include <hip/hip_runtime.h>
#include <hip/hip_bf16.h>

typedef float f4 __attribute__((ext_vector_type(4)));
typedef short bh8 __attribute__((ext_vector_type(8)));   // 8 bf16 (4 VGPRs)

#define EMB 128
#define HID 512

__device__ __forceinline__ float bfbits2f(unsigned int lo16) {
    unsigned int u = lo16 << 16;
    return __builtin_bit_cast(float, u);
}
__device__ __forceinline__ short f2bf(float f) {
    __hip_bfloat16 h = __float2bfloat16(f);
    return __builtin_bit_cast(short, h);
}
// fast GELU: x*sigmoid(1.5957691x + 0.0713548x^3); |err vs erf-GELU| <~1e-3,
// below the bf16 rounding applied to h.
__device__ __forceinline__ float gelu_fast(float x) {
    float x3 = x * x * x;
    float y = 1.5957691216f * x + 0.0713548163f * x3;
    return x / (1.0f + __expf(-y));
}

// ---------------------------------------------------------------------------
// Counting sort of edges by destination A (round-9 proven path).
// ---------------------------------------------------------------------------
__global__ void hist_kernel(const int* __restrict__ edge, unsigned* __restrict__ cnt, int E) {
    int stride = gridDim.x * blockDim.x;
    for (int e = blockIdx.x * blockDim.x + threadIdx.x; e < E; e += stride)
        atomicAdd(&cnt[edge[e]], 1u);
}

__global__ void scan_blocks(const unsigned* __restrict__ cnt, int* __restrict__ off,
                            int* __restrict__ bsum, int n) {
    __shared__ int ls[256];
    int tid = threadIdx.x;
    int base = blockIdx.x * 1024 + tid * 4;
    int v0 = 0, v1 = 0, v2 = 0, v3 = 0;
    if (base + 0 < n) v0 = (int)cnt[base + 0];
    if (base + 1 < n) v1 = (int)cnt[base + 1];
    if (base + 2 < n) v2 = (int)cnt[base + 2];
    if (base + 3 < n) v3 = (int)cnt[base + 3];
    int s = v0 + v1 + v2 + v3;
    ls[tid] = s;
    __syncthreads();
    for (int d = 1; d < 256; d <<= 1) {
        int t = (tid >= d) ? ls[tid - d] : 0;
        __syncthreads();
        ls[tid] += t;
        __syncthreads();
    }
    int incl = ls[tid];
    int run = incl - s;
    if (tid == 255) bsum[blockIdx.x] = incl;
    if (base + 0 < n) { off[base + 0] = run; run += v0; }
    if (base + 1 < n) { off[base + 1] = run; run += v1; }
    if (base + 2 < n) { off[base + 2] = run; run += v2; }
    if (base + 3 < n) { off[base + 3] = run; }
}

__global__ void scan_bsums(int* __restrict__ bsum, int nb) {
    int lane = threadIdx.x & 63;
    int x = (lane < nb) ? bsum[lane] : 0;
    int orig = x;
#pragma unroll
    for (int o = 1; o < 64; o <<= 1) {
        int t = __shfl_up(x, o, 64);
        if (lane >= o) x += t;
    }
    if (lane < nb) bsum[lane] = x - orig;
}

__global__ void scan_apply(const unsigned* __restrict__ cnt, const int* __restrict__ bsum,
                           int* __restrict__ off, int* __restrict__ offw,
                           float* __restrict__ cntf, int n) {
    int base = blockIdx.x * 1024 + threadIdx.x * 4;
    int add = bsum[blockIdx.x];
#pragma unroll
    for (int i = 0; i < 4; ++i) {
        int idx = base + i;
        if (idx < n) {
            int o = off[idx] + add;
            off[idx] = o;
            offw[idx] = o;
            cntf[idx] = (float)cnt[idx];
        }
    }
}

__global__ void place_kernel(const int* __restrict__ edge, int* __restrict__ offw,
                             int* __restrict__ sortedB, int E) {
    int stride = gridDim.x * blockDim.x;
    for (int e = blockIdx.x * blockDim.x + threadIdx.x; e < E; e += stride) {
        int a = edge[e];
        int pos = atomicAdd(&offw[a], 1);
        sortedB[pos] = edge[E + e];
    }
}

// ---------------------------------------------------------------------------
// Merged weight prep: all 6 transposes + bias concat in ONE launch.
// ---------------------------------------------------------------------------
__global__ void prep_all(const float* __restrict__ wq, const float* __restrict__ wk,
                         const float* __restrict__ wv, const float* __restrict__ wo,
                         const float* __restrict__ w1, const float* __restrict__ w2,
                         const float* __restrict__ bq, const float* __restrict__ bk,
                         const float* __restrict__ bv,
                         short* __restrict__ wqkvT, short* __restrict__ woT,
                         short* __restrict__ w1T, short* __restrict__ w2T,
                         float* __restrict__ bqkv) {
    int id = blockIdx.x * blockDim.x + threadIdx.x;
    if (id < 16384) {
        int k = id >> 7, c = id & 127;
        wqkvT[c * 128 + k] = f2bf(wq[id]);
    } else if (id < 32768) {
        int t = id - 16384; int k = t >> 7, c = t & 127;
        wqkvT[(128 + c) * 128 + k] = f2bf(wk[t]);
    } else if (id < 49152) {
        int t = id - 32768; int k = t >> 7, c = t & 127;
        wqkvT[(256 + c) * 128 + k] = f2bf(wv[t]);
    } else if (id < 65536) {
        int t = id - 49152; int k = t >> 7, c = t & 127;
        woT[c * 128 + k] = f2bf(wo[t]);
    } else if (id < 131072) {
        int t = id - 65536; int k = t >> 9, c = t & 511;
        w1T[c * 128 + k] = f2bf(w1[t]);
    } else if (id < 196608) {
        int t = id - 131072; int k = t >> 7, c = t & 127;
        w2T[c * 512 + k] = f2bf(w2[t]);
    }
    if (id < 128) {
        bqkv[id] = bq[id];
        bqkv[128 + id] = bk[id];
        bqkv[256 + id] = bv[id];
    }
}

// ---------------------------------------------------------------------------
// Fragment loader for one k-step (32 cols): 4 A frags + 4 B frags.
// ---------------------------------------------------------------------------
template<int KT, bool IN_BF16>
__device__ __forceinline__ void ld_ab(bh8 (&av)[4], bh8 (&bv)[4],
                                      const float* __restrict__ Xf, const short* __restrict__ Xb,
                                      const int (&rowA)[4], const short* __restrict__ Wt,
                                      int C0, int l15, int kbase) {
#pragma unroll
    for (int rf = 0; rf < 4; ++rf) {
        if constexpr (IN_BF16) {
            av[rf] = *(const bh8*)(Xb + (size_t)rowA[rf] * KT + kbase);
        } else {
            f4 lo = *(const f4*)(Xf + (size_t)rowA[rf] * KT + kbase);
            f4 hi = *(const f4*)(Xf + (size_t)rowA[rf] * KT + kbase + 4);
            bh8 t;
            t[0] = f2bf(lo[0]); t[1] = f2bf(lo[1]); t[2] = f2bf(lo[2]); t[3] = f2bf(lo[3]);
            t[4] = f2bf(hi[0]); t[5] = f2bf(hi[1]); t[6] = f2bf(hi[2]); t[7] = f2bf(hi[3]);
            av[rf] = t;
        }
    }
#pragma unroll
    for (int cf = 0; cf < 4; ++cf)
        bv[cf] = *(const bh8*)(Wt + (size_t)(C0 + cf * 16 + l15) * KT + kbase);
}

__device__ __forceinline__ void mm16(f4 (&acc)[4][4], const bh8 (&av)[4], const bh8 (&bv)[4]) {
#pragma unroll
    for (int rf = 0; rf < 4; ++rf)
#pragma unroll
        for (int cf = 0; cf < 4; ++cf)
            acc[rf][cf] = __builtin_amdgcn_mfma_f32_16x16x32_bf16(av[rf], bv[cf], acc[rf][cf], 0, 0, 0);
}

// ---------------------------------------------------------------------------
// MFMA GEMM (qkv / wo): 256 threads = 2x2 waves; 128x128 per block.
// 2-deep ping-pong K-pipeline. XCD-aware panel placement.
// ---------------------------------------------------------------------------
#define CSTRIDE 136   // shorts; 272B row stride: 16B-aligned, breaks kg bank aliasing

template<int KT, bool IN_BF16, bool GELU, bool OUT_BF16, bool RESID, bool RBF16, bool STATS>
__global__ __launch_bounds__(256, 2) void mfma_gemm(
    const void* __restrict__ Xv, const short* __restrict__ Wt, const float* __restrict__ bias,
    const void* __restrict__ resid,
    void* __restrict__ outv, float* __restrict__ slots, int n, int OC, int ncolb, int nrb)
{
    int bx, by;
    if (ncolb == 1) {
        bx = blockIdx.x; by = 0;
    } else {
        int q = blockIdx.x >> 3;
        by = q % ncolb;
        bx = (q / ncolb) * 8 + (blockIdx.x & 7);
        if (bx >= nrb) return;
    }
    const int lane = threadIdx.x & 63;
    const int w = threadIdx.x >> 6;
    const int wr = w >> 1, wc = w & 1;
    const int R0 = bx * 128 + wr * 64;
    const int C0 = by * 128 + wc * 64;
    const int l15 = lane & 15;
    const int kg = lane >> 4;

    const float* Xf = (const float*)Xv;
    const short* Xb = (const short*)Xv;

    int rowA[4];
#pragma unroll
    for (int rf = 0; rf < 4; ++rf) rowA[rf] = min(R0 + rf * 16 + l15, n - 1);

    f4 acc[4][4];
#pragma unroll
    for (int rf = 0; rf < 4; ++rf)
#pragma unroll
        for (int cf = 0; cf < 4; ++cf) acc[rf][cf] = 0.f;

    constexpr int NT = KT / 32;
    bh8 aA[4], bA[4], aB[4], bB[4];

    ld_ab<KT, IN_BF16>(aA, bA, Xf, Xb, rowA, Wt, C0, l15, kg * 8);
#pragma unroll
    for (int t = 0; t < NT; t += 2) {
        ld_ab<KT, IN_BF16>(aB, bB, Xf, Xb, rowA, Wt, C0, l15, (t + 1) * 32 + kg * 8);
        mm16(acc, aA, bA);
        if (t + 2 < NT)
            ld_ab<KT, IN_BF16>(aA, bA, Xf, Xb, rowA, Wt, C0, l15, (t + 2) * 32 + kg * 8);
        mm16(acc, aB, bB);
    }

    if constexpr (OUT_BF16) {
        extern __shared__ short cs[];
        const int lrb = wr * 64;
        const int lcb = wc * 64;
#pragma unroll
        for (int cf = 0; cf < 4; ++cf) {
            const float bcol = bias[C0 + cf * 16 + l15];
#pragma unroll
            for (int rf = 0; rf < 4; ++rf) {
#pragma unroll
                for (int i = 0; i < 4; ++i) {
                    float val = acc[rf][cf][i] + bcol;
                    if constexpr (GELU) val = gelu_fast(val);
                    cs[(lrb + rf * 16 + kg * 4 + i) * CSTRIDE + lcb + cf * 16 + l15] = f2bf(val);
                }
            }
        }
        __syncthreads();
        const int tc = threadIdx.x & 15;
        const int tr = threadIdx.x >> 4;
        const int gcb = by * 128;
#pragma unroll
        for (int r = 0; r < 8; ++r) {
            int lrow = tr + r * 16;
            int grow = bx * 128 + lrow;
            if (grow < n) {
                bh8 v = *(bh8*)(cs + lrow * CSTRIDE + tc * 8);
                *(bh8*)((short*)outv + (size_t)grow * OC + gcb + tc * 8) = v;
            }
        }
    } else {
#pragma unroll
        for (int cf = 0; cf < 4; ++cf) {
            const int col = C0 + cf * 16 + l15;
            const float bcol = bias[col];
#pragma unroll
            for (int rf = 0; rf < 4; ++rf) {
                float s = 0.f, q = 0.f;
#pragma unroll
                for (int i = 0; i < 4; ++i) {
                    const int row = R0 + rf * 16 + kg * 4 + i;
                    if (row < n) {
                        float val = acc[rf][cf][i] + bcol;
                        if constexpr (RESID) {
                            float rv;
                            if constexpr (RBF16)
                                rv = bfbits2f((unsigned short)((const short*)resid)[(size_t)row * EMB + col]);
                            else
                                rv = ((const float*)resid)[(size_t)row * EMB + col];
                            val += rv;
                        }
                        if constexpr (GELU) val = gelu_fast(val);
                        if constexpr (STATS) { s += val; q += val * val; }
                        ((float*)outv)[(size_t)row * OC + col] = val;
                    }
                }
                if constexpr (STATS) {
                    s += __shfl_xor(s, 16, 64); s += __shfl_xor(s, 32, 64);
                    q += __shfl_xor(q, 16, 64); q += __shfl_xor(q, 32, 64);
                    if (kg == 0) {
                        float* sl = slots + (size_t)(bx & 63) * 256;
                        unsafeAtomicAdd(&sl[col], s);
                        unsafeAtomicAdd(&sl[128 + col], q);
                    }
                }
            }
        }
    }
}

// ---------------------------------------------------------------------------
// FUSED FFN (round-16 version, measured 71.8us — best of 4 variants):
// y2 = gelu(xn1@w1+b1)@w2 + b2 + xn1, fused BN2 stats. xn1 A-frags hoisted;
// 2-deep ping-pong on B / LDS-A loads; fast GELU. 128-row blocks, block-wide
// 128-col chunks, 2 barriers/chunk. Variants that REGRESSED: per-wave
// barrier-free (r17, 96.5us: same-wave ds_write->ds_read chain + halved
// MFMA:load ratio); 64-row blocks w/ launch_bounds(256,3) (r19, 97.6us:
// VGPR squeezed to 72 -> loads de-pipelined). Fragment reuse + pipeline
// depth beat occupancy for this kernel.
// ---------------------------------------------------------------------------
__global__ __launch_bounds__(256, 2) void ffn_fused(
    const short* __restrict__ xn1, const short* __restrict__ w1T, const float* __restrict__ b1,
    const short* __restrict__ w2T, const float* __restrict__ b2,
    float* __restrict__ y2, float* __restrict__ slots, int n)
{
    extern __shared__ short hs[];   // [128][CSTRIDE] bf16
    const int bx = blockIdx.x;
    const int lane = threadIdx.x & 63;
    const int w = threadIdx.x >> 6;
    const int wr = w >> 1, wc = w & 1;
    const int R0 = bx * 128 + wr * 64;
    const int l15 = lane & 15;
    const int kg = lane >> 4;

    int rowA[4];
#pragma unroll
    for (int rf = 0; rf < 4; ++rf) rowA[rf] = min(R0 + rf * 16 + l15, n - 1);

    // hoisted xn1 A-fragments: same for every h-chunk
    bh8 aF0[4], aF1[4], aF2[4], aF3[4];
#pragma unroll
    for (int rf = 0; rf < 4; ++rf) {
        const short* p = xn1 + (size_t)rowA[rf] * EMB + kg * 8;
        aF0[rf] = *(const bh8*)(p);
        aF1[rf] = *(const bh8*)(p + 32);
        aF2[rf] = *(const bh8*)(p + 64);
        aF3[rf] = *(const bh8*)(p + 96);
    }

    f4 acc2[4][4];
#pragma unroll
    for (int rf = 0; rf < 4; ++rf)
#pragma unroll
        for (int cf = 0; cf < 4; ++cf) acc2[rf][cf] = 0.f;

    const int lrb = wr * 64;
    const int lcb = wc * 64;

    for (int c = 0; c < 4; ++c) {
        // ---- FC1 chunk: acc1 = xn1 @ w1T[cols c*128+wc*64 .. +63] ----
        f4 acc1[4][4];
#pragma unroll
        for (int rf = 0; rf < 4; ++rf)
#pragma unroll
            for (int cf = 0; cf < 4; ++cf) acc1[rf][cf] = 0.f;

        bh8 bP[4], bQ[4];
        auto ldB1 = [&](bh8 (&dst)[4], int ks) {
#pragma unroll
            for (int cf = 0; cf < 4; ++cf) {
                int col = c * 128 + wc * 64 + cf * 16 + l15;
                dst[cf] = *(const bh8*)(w1T + (size_t)col * EMB + ks * 32 + kg * 8);
            }
        };
        ldB1(bP, 0);
        ldB1(bQ, 1);
        mm16(acc1, aF0, bP);
        ldB1(bP, 2);
        mm16(acc1, aF1, bQ);
        ldB1(bQ, 3);
        mm16(acc1, aF2, bP);
        mm16(acc1, aF3, bQ);

        // ---- fast GELU -> LDS tile ----
        __syncthreads();   // protect previous chunk's LDS reads
#pragma unroll
        for (int cf = 0; cf < 4; ++cf) {
            const float bcol = b1[c * 128 + wc * 64 + cf * 16 + l15];
#pragma unroll
            for (int rf = 0; rf < 4; ++rf) {
#pragma unroll
                for (int i = 0; i < 4; ++i) {
                    float val = gelu_fast(acc1[rf][cf][i] + bcol);
                    hs[(lrb + rf * 16 + kg * 4 + i) * CSTRIDE + lcb + cf * 16 + l15] = f2bf(val);
                }
            }
        }
        __syncthreads();

        // ---- FC2 partial: acc2 += h_chunk @ w2T[:, c*128..] ----
        bh8 aP[4], aQ[4];
        auto ldA2 = [&](bh8 (&dst)[4], int ks) {
#pragma unroll
            for (int rf = 0; rf < 4; ++rf)
                dst[rf] = *(const bh8*)(hs + (wr * 64 + rf * 16 + l15) * CSTRIDE + ks * 32 + kg * 8);
        };
        auto ldB2 = [&](bh8 (&dst)[4], int ks) {
#pragma unroll
            for (int cf = 0; cf < 4; ++cf) {
                int col = wc * 64 + cf * 16 + l15;
                dst[cf] = *(const bh8*)(w2T + (size_t)col * HID + c * 128 + ks * 32 + kg * 8);
            }
        };
        ldA2(aP, 0); ldB2(bP, 0);
        ldA2(aQ, 1); ldB2(bQ, 1);
        mm16(acc2, aP, bP);
        ldA2(aP, 2); ldB2(bP, 2);
        mm16(acc2, aQ, bQ);
        ldA2(aQ, 3); ldB2(bQ, 3);
        mm16(acc2, aP, bP);
        mm16(acc2, aQ, bQ);
    }

    // ---- epilogue: y2 = acc2 + b2 + xn1 (bf16 resid), fused BN2 stats ----
    const int C0 = wc * 64;
#pragma unroll
    for (int cf = 0; cf < 4; ++cf) {
        const int col = C0 + cf * 16 + l15;
        const float bcol = b2[col];
#pragma unroll
        for (int rf = 0; rf < 4; ++rf) {
            float s = 0.f, q = 0.f;
#pragma unroll
            for (int i = 0; i < 4; ++i) {
                const int row = R0 + rf * 16 + kg * 4 + i;
                if (row < n) {
                    float val = acc2[rf][cf][i] + bcol;
                    val += bfbits2f((unsigned short)xn1[(size_t)row * EMB + col]);
                    s += val; q += val * val;
                    y2[(size_t)row * EMB + col] = val;
                }
            }
            s += __shfl_xor(s, 16, 64); s += __shfl_xor(s, 32, 64);
            q += __shfl_xor(q, 16, 64); q += __shfl_xor(q, 32, 64);
            if (kg == 0) {
                float* sl = slots + (size_t)(bx & 63) * 256;
                unsafeAtomicAdd(&sl[col], s);
                unsafeAtomicAdd(&sl[128 + col], q);
            }
        }
    }
}

// ---------------------------------------------------------------------------
// FUSED gather+attention (round-14 vector-load version).
// ---------------------------------------------------------------------------
__global__ void gather_attn_kernel(const short* __restrict__ qkv, const int* __restrict__ off,
                                   const unsigned* __restrict__ cnt, const int* __restrict__ sortedB,
                                   const float* __restrict__ cntf, short* __restrict__ attno, int n) {
    int wid = (int)((blockIdx.x * blockDim.x + threadIdx.x) >> 6);
    int lane = threadIdx.x & 63;
    int nw = (gridDim.x * blockDim.x) >> 6;
    const int l15 = lane & 15;
    const int grp = lane >> 4;
    const int h = lane >> 3, g = lane & 7;
    for (int node = wid; node < n; node += nw) {
        int start = off[node];
        int deg = (int)cnt[node];
        float a[8];
#pragma unroll
        for (int i = 0; i < 8; ++i) a[i] = 0.f;
        for (int j = 0; j < deg; j += 8) {
            int i0 = j + grp, i1 = j + 4 + grp;
            uint4 u0 = make_uint4(0, 0, 0, 0), u1 = make_uint4(0, 0, 0, 0);
            if (i0 < deg) {
                int b = sortedB[start + i0];
                u0 = *(const uint4*)(qkv + (size_t)b * 384 + 128 + l15 * 8);
            }
            if (i1 < deg) {
                int b = sortedB[start + i1];
                u1 = *(const uint4*)(qkv + (size_t)b * 384 + 128 + l15 * 8);
            }
            unsigned w0[4] = {u0.x, u0.y, u0.z, u0.w};
            unsigned w1[4] = {u1.x, u1.y, u1.z, u1.w};
#pragma unroll
            for (int i = 0; i < 4; ++i) {
                a[2 * i]     += bfbits2f(w0[i] & 0xffffu) + bfbits2f(w1[i] & 0xffffu);
                a[2 * i + 1] += bfbits2f(w0[i] >> 16)     + bfbits2f(w1[i] >> 16);
            }
        }
#pragma unroll
        for (int i = 0; i < 8; ++i) {
            a[i] += __shfl_xor(a[i], 16, 64);
            a[i] += __shfl_xor(a[i], 32, 64);
        }

        const short* qp = qkv + (size_t)node * 384 + h * 16;
        uint4 qa = *(const uint4*)qp;
        uint4 qb = *(const uint4*)(qp + 8);
        float qv[16];
        {
            unsigned ua[4] = {qa.x, qa.y, qa.z, qa.w};
            unsigned ub[4] = {qb.x, qb.y, qb.z, qb.w};
#pragma unroll
            for (int w2 = 0; w2 < 4; ++w2) {
                qv[2 * w2]         = bfbits2f(ua[w2] & 0xffffu);
                qv[2 * w2 + 1]     = bfbits2f(ua[w2] >> 16);
                qv[8 + 2 * w2]     = bfbits2f(ub[w2] & 0xffffu);
                qv[8 + 2 * w2 + 1] = bfbits2f(ub[w2] >> 16);
            }
        }
        float s = 0.f;
#pragma unroll
        for (int i = 0; i < 8; ++i) {
            s += qv[i]     * __shfl(a[i], 2 * g, 64);
            s += qv[8 + i] * __shfl(a[i], 2 * g + 1, 64);
        }
        float c = cntf[node];
        s *= 1.0f / fmaxf(c, 1.0f);
        float m = s;
#pragma unroll
        for (int o = 1; o < 8; o <<= 1) m = fmaxf(m, __shfl_xor(m, o, 64));
        float e = __expf(s - m);
        float sum = e;
#pragma unroll
        for (int o = 1; o < 8; o <<= 1) sum += __shfl_xor(sum, o, 64);
        float p = e / sum;
        float o0 = 0.f, o1 = 0.f;
        int d0 = g * 2;
#pragma unroll
        for (int gg = 0; gg < 8; ++gg) {
            float pg = __shfl(p, h * 8 + gg, 64);
            unsigned vv = *(const unsigned*)(qkv + (size_t)node * 384 + 256 + gg * 16 + d0);
            o0 += pg * bfbits2f(vv & 0xffffu);
            o1 += pg * bfbits2f(vv >> 16);
        }
        unsigned pk = (unsigned)(unsigned short)f2bf(o0) | ((unsigned)(unsigned short)f2bf(o1) << 16);
        *(unsigned*)(attno + (size_t)node * EMB + h * 16 + d0) = pk;
    }
}

// ---------------------------------------------------------------------------
// BatchNorm helpers
// ---------------------------------------------------------------------------
__global__ void bn_finalize_slots(const float* __restrict__ slots, float* __restrict__ scsh,
                                  const float* __restrict__ g, const float* __restrict__ be, int n) {
    int c = threadIdx.x;
    float s = 0.f, q = 0.f;
    for (int i = 0; i < 64; ++i) {
        s += slots[(size_t)i * 256 + c];
        q += slots[(size_t)i * 256 + 128 + c];
    }
    float invn = 1.0f / (float)n;
    float mean = s * invn;
    float var = fmaxf(q * invn - mean * mean, 0.f);
    float sc = g[c] * rsqrtf(var + 1e-5f);
    scsh[c] = sc;
    scsh[128 + c] = be[c] - mean * sc;
}

// xn1 = bf16(bn1(y1)) : read fp32, apply scale/shift, write bf16
__global__ void apply_bn_bf16(const float* __restrict__ Y, const float* __restrict__ scsh,
                              short* __restrict__ out, size_t total8) {
    size_t stride = (size_t)gridDim.x * blockDim.x;
    for (size_t i = (size_t)blockIdx.x * blockDim.x + threadIdx.x; i < total8; i += stride) {
        size_t base = i * 8;
        f4 lo = *(const f4*)(Y + base);
        f4 hi = *(const f4*)(Y + base + 4);
        int c = (int)(base & 127);
        f4 s0 = *(const f4*)(scsh + c);
        f4 s1 = *(const f4*)(scsh + c + 4);
        f4 h0 = *(const f4*)(scsh + 128 + c);
        f4 h1 = *(const f4*)(scsh + 128 + c + 4);
        lo = lo * s0 + h0;
        hi = hi * s1 + h1;
        bh8 o;
        o[0] = f2bf(lo[0]); o[1] = f2bf(lo[1]); o[2] = f2bf(lo[2]); o[3] = f2bf(lo[3]);
        o[4] = f2bf(hi[0]); o[5] = f2bf(hi[1]); o[6] = f2bf(hi[2]); o[7] = f2bf(hi[3]);
        *(bh8*)(out + base) = o;
    }
}

__global__ void bn_apply(float* __restrict__ Y, const float* __restrict__ scsh, size_t total4) {
    size_t stride = (size_t)gridDim.x * blockDim.x;
    for (size_t i = (size_t)blockIdx.x * blockDim.x + threadIdx.x; i < total4; i += stride) {
        f4 vv = ((f4*)Y)[i];
        int c = (int)((i * 4) & 127);
#pragma unroll
        for (int j = 0; j < 4; ++j) vv[j] = vv[j] * scsh[c + j] + scsh[128 + c + j];
        ((f4*)Y)[i] = vv;
    }
}

// ---------------------------------------------------------------------------
extern "C" void kernel_launch(void* const* d_in, const int* in_sizes, int n_in,
                              void* d_out, int out_size, void* d_ws, size_t ws_size,
                              hipStream_t stream) {
    const float* x   = (const float*)d_in[0];
    const float* wq  = (const float*)d_in[1];
    const float* bq  = (const float*)d_in[2];
    const float* wk  = (const float*)d_in[3];
    const float* bk  = (const float*)d_in[4];
    const float* wv  = (const float*)d_in[5];
    const float* bv  = (const float*)d_in[6];
    const float* wo  = (const float*)d_in[7];
    const float* bo  = (const float*)d_in[8];
    const float* w1  = (const float*)d_in[9];
    const float* b1  = (const float*)d_in[10];
    const float* w2  = (const float*)d_in[11];
    const float* b2  = (const float*)d_in[12];
    const float* g1  = (const float*)d_in[13];
    const float* be1 = (const float*)d_in[14];
    const float* g2  = (const float*)d_in[15];
    const float* be2 = (const float*)d_in[16];
    const int* edge  = (const int*)d_in[17];

    int n = in_sizes[0] / EMB;      // 50000
    int E = in_sizes[17] / 2;       // 800000

    // workspace layout (float units)
    float* wsf = (float*)d_ws;
    unsigned* cnt_u = (unsigned*)wsf;                       // 65536
    float*  cntf  = wsf + 65536;                            // 65536
    int*    off   = (int*)(wsf + 2 * 65536);                // 65536
    int*    offw  = (int*)(wsf + 3 * 65536);                // 65536
    int*    bsum  = (int*)(wsf + 4 * 65536);                // 64
    int*    sortedB = (int*)(wsf + 4 * 65536 + 64);         // E
    float*  base5 = wsf + 4 * 65536 + 64 + E;
    short*  qkv   = (short*)base5;                          // n*384 bf16 = n*192 f
    short*  attno = (short*)(base5 + (size_t)n * 256);      // n*128 bf16
    float*  y1    = base5 + (size_t)n * 320;                // n*128 f
    float*  warea = y1 + (size_t)n * 128;
    short*  wqkvT = (short*)warea;                          // 384*128 bf16
    short*  woT   = wqkvT + 384 * 128;                      // 128*128
    short*  w1T   = woT + 128 * 128;                        // 512*128
    short*  w2T   = w1T + 512 * 128;                        // 128*512
    float*  bqkv  = (float*)(w2T + 128 * 512);              // 384
    float*  slots1 = bqkv + 384;                            // 64*256
    float*  slots2 = slots1 + 64 * 256;                     // 64*256
    float*  scsh1  = slots2 + 64 * 256;                     // 256
    float*  scsh2  = scsh1 + 256;                           // 256
    short*  xn1   = attno;                                  // n*128 bf16 (attno dead after wo-GEMM)
    float*  y2    = (float*)d_out;

    hipMemsetAsync(cnt_u, 0, 65536 * sizeof(unsigned), stream);
    hipMemsetAsync(slots1, 0, 2 * 64 * 256 * sizeof(float), stream);

    // edge counting sort
    int nb = (n + 1023) / 1024;  // 49
    hist_kernel<<<2048, 256, 0, stream>>>(edge, cnt_u, E);
    scan_blocks<<<nb, 256, 0, stream>>>(cnt_u, off, bsum, n);
    scan_bsums<<<1, 64, 0, stream>>>(bsum, nb);
    scan_apply<<<nb, 256, 0, stream>>>(cnt_u, bsum, off, offw, cntf, n);
    place_kernel<<<2048, 256, 0, stream>>>(edge, offw, sortedB, E);

    // merged weight prep (6 transposes + bias concat, one launch)
    prep_all<<<768, 256, 0, stream>>>(wq, wk, wv, wo, w1, w2, bq, bk, bv,
                                      wqkvT, woT, w1T, w2T, bqkv);

    int nrb = (n + 127) / 128;              // 391 row-groups
    int nrb8 = ((nrb + 7) / 8) * 8;         // 392, XCD-aligned
    const size_t CSH = 128 * CSTRIDE * sizeof(short);  // 34816 B

    // qkv = x @ [wq|wk|wv] + bqkv  (fp32 in, converted in-reg; bf16 out [n][384])
    mfma_gemm<128, false, false, true, false, false, false><<<nrb8 * 3, 256, CSH, stream>>>(
        x, wqkvT, bqkv, nullptr, qkv, nullptr, n, 384, 3, nrb);

    // fused: ksum gather (in regs, vector loads) + attention -> attno
    gather_attn_kernel<<<2048, 256, 0, stream>>>(qkv, off, cnt_u, sortedB, cntf, attno, n);

    // y1 = attno@wo + bo + x (fp32 out) + fused BN1 stats
    mfma_gemm<128, true, false, false, true, false, true><<<nrb, 256, 0, stream>>>(
        attno, woT, bo, x, y1, slots1, n, EMB, 1, nrb);

    bn_finalize_slots<<<1, 128, 0, stream>>>(slots1, scsh1, g1, be1, n);

    // xn1 = bf16(bn1(y1))  (overwrites attno region; attno is dead)
    apply_bn_bf16<<<1600, 256, 0, stream>>>(y1, scsh1, xn1, (size_t)n * EMB / 8);

    // FUSED FFN: y2 = gelu(xn1@w1+b1)@w2 + b2 + xn1, + BN2 stats
    ffn_fused<<<nrb, 256, CSH, stream>>>(xn1, w1T, b1, w2T, b2, y2, slots2, n);

    bn_finalize_slots<<<1, 128, 0, stream>>>(slots2, scsh2, g2, be2, n);
    bn_apply<<<512, 256, 0, stream>>>(y2, scsh2, (size_t)n * EMB / 4);
}

// Round 21
// 300.914 us; speedup vs baseline: 1.0742x; 1.0134x over previous
//
#include <hip/hip_runtime.h>
#include <hip/hip_bf16.h>

typedef float f4 __attribute__((ext_vector_type(4)));
typedef short bh8 __attribute__((ext_vector_type(8)));   // 8 bf16 (4 VGPRs)

#define EMB 128
#define HID 512

__device__ __forceinline__ float bfbits2f(unsigned int lo16) {
    unsigned int u = lo16 << 16;
    return __builtin_bit_cast(float, u);
}
__device__ __forceinline__ short f2bf(float f) {
    __hip_bfloat16 h = __float2bfloat16(f);
    return __builtin_bit_cast(short, h);
}
// fast GELU: x*sigmoid(1.5957691x + 0.0713548x^3); |err vs erf-GELU| <~1e-3,
// below the bf16 rounding applied to h.
__device__ __forceinline__ float gelu_fast(float x) {
    float x3 = x * x * x;
    float y = 1.5957691216f * x + 0.0713548163f * x3;
    return x / (1.0f + __expf(-y));
}

// ---------------------------------------------------------------------------
// Counting sort of edges by destination A (round-9 proven path).
// ---------------------------------------------------------------------------
__global__ void hist_kernel(const int* __restrict__ edge, unsigned* __restrict__ cnt, int E) {
    int stride = gridDim.x * blockDim.x;
    for (int e = blockIdx.x * blockDim.x + threadIdx.x; e < E; e += stride)
        atomicAdd(&cnt[edge[e]], 1u);
}

__global__ void scan_blocks(const unsigned* __restrict__ cnt, int* __restrict__ off,
                            int* __restrict__ bsum, int n) {
    __shared__ int ls[256];
    int tid = threadIdx.x;
    int base = blockIdx.x * 1024 + tid * 4;
    int v0 = 0, v1 = 0, v2 = 0, v3 = 0;
    if (base + 0 < n) v0 = (int)cnt[base + 0];
    if (base + 1 < n) v1 = (int)cnt[base + 1];
    if (base + 2 < n) v2 = (int)cnt[base + 2];
    if (base + 3 < n) v3 = (int)cnt[base + 3];
    int s = v0 + v1 + v2 + v3;
    ls[tid] = s;
    __syncthreads();
    for (int d = 1; d < 256; d <<= 1) {
        int t = (tid >= d) ? ls[tid - d] : 0;
        __syncthreads();
        ls[tid] += t;
        __syncthreads();
    }
    int incl = ls[tid];
    int run = incl - s;
    if (tid == 255) bsum[blockIdx.x] = incl;
    if (base + 0 < n) { off[base + 0] = run; run += v0; }
    if (base + 1 < n) { off[base + 1] = run; run += v1; }
    if (base + 2 < n) { off[base + 2] = run; run += v2; }
    if (base + 3 < n) { off[base + 3] = run; }
}

__global__ void scan_bsums(int* __restrict__ bsum, int nb) {
    int lane = threadIdx.x & 63;
    int x = (lane < nb) ? bsum[lane] : 0;
    int orig = x;
#pragma unroll
    for (int o = 1; o < 64; o <<= 1) {
        int t = __shfl_up(x, o, 64);
        if (lane >= o) x += t;
    }
    if (lane < nb) bsum[lane] = x - orig;
}

__global__ void scan_apply(const unsigned* __restrict__ cnt, const int* __restrict__ bsum,
                           int* __restrict__ off, int* __restrict__ offw,
                           float* __restrict__ cntf, int n) {
    int base = blockIdx.x * 1024 + threadIdx.x * 4;
    int add = bsum[blockIdx.x];
#pragma unroll
    for (int i = 0; i < 4; ++i) {
        int idx = base + i;
        if (idx < n) {
            int o = off[idx] + add;
            off[idx] = o;
            offw[idx] = o;
            cntf[idx] = (float)cnt[idx];
        }
    }
}

__global__ void place_kernel(const int* __restrict__ edge, int* __restrict__ offw,
                             int* __restrict__ sortedB, int E) {
    int stride = gridDim.x * blockDim.x;
    for (int e = blockIdx.x * blockDim.x + threadIdx.x; e < E; e += stride) {
        int a = edge[e];
        int pos = atomicAdd(&offw[a], 1);
        sortedB[pos] = edge[E + e];
    }
}

// ---------------------------------------------------------------------------
// Merged weight prep: all 6 transposes + bias concat in ONE launch.
// ---------------------------------------------------------------------------
__global__ void prep_all(const float* __restrict__ wq, const float* __restrict__ wk,
                         const float* __restrict__ wv, const float* __restrict__ wo,
                         const float* __restrict__ w1, const float* __restrict__ w2,
                         const float* __restrict__ bq, const float* __restrict__ bk,
                         const float* __restrict__ bv,
                         short* __restrict__ wqkvT, short* __restrict__ woT,
                         short* __restrict__ w1T, short* __restrict__ w2T,
                         float* __restrict__ bqkv) {
    int id = blockIdx.x * blockDim.x + threadIdx.x;
    if (id < 16384) {
        int k = id >> 7, c = id & 127;
        wqkvT[c * 128 + k] = f2bf(wq[id]);
    } else if (id < 32768) {
        int t = id - 16384; int k = t >> 7, c = t & 127;
        wqkvT[(128 + c) * 128 + k] = f2bf(wk[t]);
    } else if (id < 49152) {
        int t = id - 32768; int k = t >> 7, c = t & 127;
        wqkvT[(256 + c) * 128 + k] = f2bf(wv[t]);
    } else if (id < 65536) {
        int t = id - 49152; int k = t >> 7, c = t & 127;
        woT[c * 128 + k] = f2bf(wo[t]);
    } else if (id < 131072) {
        int t = id - 65536; int k = t >> 9, c = t & 511;
        w1T[c * 128 + k] = f2bf(w1[t]);
    } else if (id < 196608) {
        int t = id - 131072; int k = t >> 7, c = t & 127;
        w2T[c * 512 + k] = f2bf(w2[t]);
    }
    if (id < 128) {
        bqkv[id] = bq[id];
        bqkv[128 + id] = bk[id];
        bqkv[256 + id] = bv[id];
    }
}

// ---------------------------------------------------------------------------
// Fragment loader for one k-step (32 cols): 4 A frags + 4 B frags.
// ---------------------------------------------------------------------------
template<int KT, bool IN_BF16>
__device__ __forceinline__ void ld_ab(bh8 (&av)[4], bh8 (&bv)[4],
                                      const float* __restrict__ Xf, const short* __restrict__ Xb,
                                      const int (&rowA)[4], const short* __restrict__ Wt,
                                      int C0, int l15, int kbase) {
#pragma unroll
    for (int rf = 0; rf < 4; ++rf) {
        if constexpr (IN_BF16) {
            av[rf] = *(const bh8*)(Xb + (size_t)rowA[rf] * KT + kbase);
        } else {
            f4 lo = *(const f4*)(Xf + (size_t)rowA[rf] * KT + kbase);
            f4 hi = *(const f4*)(Xf + (size_t)rowA[rf] * KT + kbase + 4);
            bh8 t;
            t[0] = f2bf(lo[0]); t[1] = f2bf(lo[1]); t[2] = f2bf(lo[2]); t[3] = f2bf(lo[3]);
            t[4] = f2bf(hi[0]); t[5] = f2bf(hi[1]); t[6] = f2bf(hi[2]); t[7] = f2bf(hi[3]);
            av[rf] = t;
        }
    }
#pragma unroll
    for (int cf = 0; cf < 4; ++cf)
        bv[cf] = *(const bh8*)(Wt + (size_t)(C0 + cf * 16 + l15) * KT + kbase);
}

__device__ __forceinline__ void mm16(f4 (&acc)[4][4], const bh8 (&av)[4], const bh8 (&bv)[4]) {
#pragma unroll
    for (int rf = 0; rf < 4; ++rf)
#pragma unroll
        for (int cf = 0; cf < 4; ++cf)
            acc[rf][cf] = __builtin_amdgcn_mfma_f32_16x16x32_bf16(av[rf], bv[cf], acc[rf][cf], 0, 0, 0);
}

// ---------------------------------------------------------------------------
// MFMA GEMM (qkv / wo): 256 threads = 2x2 waves; 128x128 per block.
// 2-deep ping-pong K-pipeline. XCD-aware panel placement.
// ---------------------------------------------------------------------------
#define CSTRIDE 136   // shorts; 272B row stride: 16B-aligned, breaks kg bank aliasing

template<int KT, bool IN_BF16, bool GELU, bool OUT_BF16, bool RESID, bool RBF16, bool STATS>
__global__ __launch_bounds__(256, 2) void mfma_gemm(
    const void* __restrict__ Xv, const short* __restrict__ Wt, const float* __restrict__ bias,
    const void* __restrict__ resid,
    void* __restrict__ outv, float* __restrict__ slots, int n, int OC, int ncolb, int nrb)
{
    int bx, by;
    if (ncolb == 1) {
        bx = blockIdx.x; by = 0;
    } else {
        int q = blockIdx.x >> 3;
        by = q % ncolb;
        bx = (q / ncolb) * 8 + (blockIdx.x & 7);
        if (bx >= nrb) return;
    }
    const int lane = threadIdx.x & 63;
    const int w = threadIdx.x >> 6;
    const int wr = w >> 1, wc = w & 1;
    const int R0 = bx * 128 + wr * 64;
    const int C0 = by * 128 + wc * 64;
    const int l15 = lane & 15;
    const int kg = lane >> 4;

    const float* Xf = (const float*)Xv;
    const short* Xb = (const short*)Xv;

    int rowA[4];
#pragma unroll
    for (int rf = 0; rf < 4; ++rf) rowA[rf] = min(R0 + rf * 16 + l15, n - 1);

    f4 acc[4][4];
#pragma unroll
    for (int rf = 0; rf < 4; ++rf)
#pragma unroll
        for (int cf = 0; cf < 4; ++cf) acc[rf][cf] = 0.f;

    constexpr int NT = KT / 32;
    bh8 aA[4], bA[4], aB[4], bB[4];

    ld_ab<KT, IN_BF16>(aA, bA, Xf, Xb, rowA, Wt, C0, l15, kg * 8);
#pragma unroll
    for (int t = 0; t < NT; t += 2) {
        ld_ab<KT, IN_BF16>(aB, bB, Xf, Xb, rowA, Wt, C0, l15, (t + 1) * 32 + kg * 8);
        mm16(acc, aA, bA);
        if (t + 2 < NT)
            ld_ab<KT, IN_BF16>(aA, bA, Xf, Xb, rowA, Wt, C0, l15, (t + 2) * 32 + kg * 8);
        mm16(acc, aB, bB);
    }

    if constexpr (OUT_BF16) {
        extern __shared__ short cs[];
        const int lrb = wr * 64;
        const int lcb = wc * 64;
#pragma unroll
        for (int cf = 0; cf < 4; ++cf) {
            const float bcol = bias[C0 + cf * 16 + l15];
#pragma unroll
            for (int rf = 0; rf < 4; ++rf) {
#pragma unroll
                for (int i = 0; i < 4; ++i) {
                    float val = acc[rf][cf][i] + bcol;
                    if constexpr (GELU) val = gelu_fast(val);
                    cs[(lrb + rf * 16 + kg * 4 + i) * CSTRIDE + lcb + cf * 16 + l15] = f2bf(val);
                }
            }
        }
        __syncthreads();
        const int tc = threadIdx.x & 15;
        const int tr = threadIdx.x >> 4;
        const int gcb = by * 128;
#pragma unroll
        for (int r = 0; r < 8; ++r) {
            int lrow = tr + r * 16;
            int grow = bx * 128 + lrow;
            if (grow < n) {
                bh8 v = *(bh8*)(cs + lrow * CSTRIDE + tc * 8);
                *(bh8*)((short*)outv + (size_t)grow * OC + gcb + tc * 8) = v;
            }
        }
    } else {
#pragma unroll
        for (int cf = 0; cf < 4; ++cf) {
            const int col = C0 + cf * 16 + l15;
            const float bcol = bias[col];
#pragma unroll
            for (int rf = 0; rf < 4; ++rf) {
                float s = 0.f, q = 0.f;
#pragma unroll
                for (int i = 0; i < 4; ++i) {
                    const int row = R0 + rf * 16 + kg * 4 + i;
                    if (row < n) {
                        float val = acc[rf][cf][i] + bcol;
                        if constexpr (RESID) {
                            float rv;
                            if constexpr (RBF16)
                                rv = bfbits2f((unsigned short)((const short*)resid)[(size_t)row * EMB + col]);
                            else
                                rv = ((const float*)resid)[(size_t)row * EMB + col];
                            val += rv;
                        }
                        if constexpr (GELU) val = gelu_fast(val);
                        if constexpr (STATS) { s += val; q += val * val; }
                        ((float*)outv)[(size_t)row * OC + col] = val;
                    }
                }
                if constexpr (STATS) {
                    s += __shfl_xor(s, 16, 64); s += __shfl_xor(s, 32, 64);
                    q += __shfl_xor(q, 16, 64); q += __shfl_xor(q, 32, 64);
                    if (kg == 0) {
                        float* sl = slots + (size_t)(bx & 63) * 256;
                        unsafeAtomicAdd(&sl[col], s);
                        unsafeAtomicAdd(&sl[128 + col], q);
                    }
                }
            }
        }
    }
}

// ---------------------------------------------------------------------------
// FUSED FFN (round-16 version, measured 71.8us — best of 4 variants):
// y2 = gelu(xn1@w1+b1)@w2 + b2 + xn1, fused BN2 stats. xn1 A-frags hoisted;
// 2-deep ping-pong on B / LDS-A loads; fast GELU. 128-row blocks, block-wide
// 128-col chunks, 2 barriers/chunk. Variants that REGRESSED: per-wave
// barrier-free (r17, 96.5us); 64-row blocks w/ launch_bounds(256,3) (r19,
// 97.6us: VGPR squeezed to 72 -> loads de-pipelined). Fragment reuse +
// pipeline depth beat occupancy for this kernel.
// ---------------------------------------------------------------------------
__global__ __launch_bounds__(256, 2) void ffn_fused(
    const short* __restrict__ xn1, const short* __restrict__ w1T, const float* __restrict__ b1,
    const short* __restrict__ w2T, const float* __restrict__ b2,
    float* __restrict__ y2, float* __restrict__ slots, int n)
{
    extern __shared__ short hs[];   // [128][CSTRIDE] bf16
    const int bx = blockIdx.x;
    const int lane = threadIdx.x & 63;
    const int w = threadIdx.x >> 6;
    const int wr = w >> 1, wc = w & 1;
    const int R0 = bx * 128 + wr * 64;
    const int l15 = lane & 15;
    const int kg = lane >> 4;

    int rowA[4];
#pragma unroll
    for (int rf = 0; rf < 4; ++rf) rowA[rf] = min(R0 + rf * 16 + l15, n - 1);

    // hoisted xn1 A-fragments: same for every h-chunk
    bh8 aF0[4], aF1[4], aF2[4], aF3[4];
#pragma unroll
    for (int rf = 0; rf < 4; ++rf) {
        const short* p = xn1 + (size_t)rowA[rf] * EMB + kg * 8;
        aF0[rf] = *(const bh8*)(p);
        aF1[rf] = *(const bh8*)(p + 32);
        aF2[rf] = *(const bh8*)(p + 64);
        aF3[rf] = *(const bh8*)(p + 96);
    }

    f4 acc2[4][4];
#pragma unroll
    for (int rf = 0; rf < 4; ++rf)
#pragma unroll
        for (int cf = 0; cf < 4; ++cf) acc2[rf][cf] = 0.f;

    const int lrb = wr * 64;
    const int lcb = wc * 64;

    for (int c = 0; c < 4; ++c) {
        // ---- FC1 chunk: acc1 = xn1 @ w1T[cols c*128+wc*64 .. +63] ----
        f4 acc1[4][4];
#pragma unroll
        for (int rf = 0; rf < 4; ++rf)
#pragma unroll
            for (int cf = 0; cf < 4; ++cf) acc1[rf][cf] = 0.f;

        bh8 bP[4], bQ[4];
        auto ldB1 = [&](bh8 (&dst)[4], int ks) {
#pragma unroll
            for (int cf = 0; cf < 4; ++cf) {
                int col = c * 128 + wc * 64 + cf * 16 + l15;
                dst[cf] = *(const bh8*)(w1T + (size_t)col * EMB + ks * 32 + kg * 8);
            }
        };
        ldB1(bP, 0);
        ldB1(bQ, 1);
        mm16(acc1, aF0, bP);
        ldB1(bP, 2);
        mm16(acc1, aF1, bQ);
        ldB1(bQ, 3);
        mm16(acc1, aF2, bP);
        mm16(acc1, aF3, bQ);

        // ---- fast GELU -> LDS tile ----
        __syncthreads();   // protect previous chunk's LDS reads
#pragma unroll
        for (int cf = 0; cf < 4; ++cf) {
            const float bcol = b1[c * 128 + wc * 64 + cf * 16 + l15];
#pragma unroll
            for (int rf = 0; rf < 4; ++rf) {
#pragma unroll
                for (int i = 0; i < 4; ++i) {
                    float val = gelu_fast(acc1[rf][cf][i] + bcol);
                    hs[(lrb + rf * 16 + kg * 4 + i) * CSTRIDE + lcb + cf * 16 + l15] = f2bf(val);
                }
            }
        }
        __syncthreads();

        // ---- FC2 partial: acc2 += h_chunk @ w2T[:, c*128..] ----
        bh8 aP[4], aQ[4];
        auto ldA2 = [&](bh8 (&dst)[4], int ks) {
#pragma unroll
            for (int rf = 0; rf < 4; ++rf)
                dst[rf] = *(const bh8*)(hs + (wr * 64 + rf * 16 + l15) * CSTRIDE + ks * 32 + kg * 8);
        };
        auto ldB2 = [&](bh8 (&dst)[4], int ks) {
#pragma unroll
            for (int cf = 0; cf < 4; ++cf) {
                int col = wc * 64 + cf * 16 + l15;
                dst[cf] = *(const bh8*)(w2T + (size_t)col * HID + c * 128 + ks * 32 + kg * 8);
            }
        };
        ldA2(aP, 0); ldB2(bP, 0);
        ldA2(aQ, 1); ldB2(bQ, 1);
        mm16(acc2, aP, bP);
        ldA2(aP, 2); ldB2(bP, 2);
        mm16(acc2, aQ, bQ);
        ldA2(aQ, 3); ldB2(bQ, 3);
        mm16(acc2, aP, bP);
        mm16(acc2, aQ, bQ);
    }

    // ---- epilogue: y2 = acc2 + b2 + xn1 (bf16 resid), fused BN2 stats ----
    const int C0 = wc * 64;
#pragma unroll
    for (int cf = 0; cf < 4; ++cf) {
        const int col = C0 + cf * 16 + l15;
        const float bcol = b2[col];
#pragma unroll
        for (int rf = 0; rf < 4; ++rf) {
            float s = 0.f, q = 0.f;
#pragma unroll
            for (int i = 0; i < 4; ++i) {
                const int row = R0 + rf * 16 + kg * 4 + i;
                if (row < n) {
                    float val = acc2[rf][cf][i] + bcol;
                    val += bfbits2f((unsigned short)xn1[(size_t)row * EMB + col]);
                    s += val; q += val * val;
                    y2[(size_t)row * EMB + col] = val;
                }
            }
            s += __shfl_xor(s, 16, 64); s += __shfl_xor(s, 32, 64);
            q += __shfl_xor(q, 16, 64); q += __shfl_xor(q, 32, 64);
            if (kg == 0) {
                float* sl = slots + (size_t)(bx & 63) * 256;
                unsafeAtomicAdd(&sl[col], s);
                unsafeAtomicAdd(&sl[128 + col], q);
            }
        }
    }
}

// ---------------------------------------------------------------------------
// FUSED gather+attention (round-14 vector-load version).
// Grid raised 2048->6144 blocks: pure random-load latency kernel (VGPR 36),
// more resident waves = more loads in flight.
// ---------------------------------------------------------------------------
__global__ void gather_attn_kernel(const short* __restrict__ qkv, const int* __restrict__ off,
                                   const unsigned* __restrict__ cnt, const int* __restrict__ sortedB,
                                   const float* __restrict__ cntf, short* __restrict__ attno, int n) {
    int wid = (int)((blockIdx.x * blockDim.x + threadIdx.x) >> 6);
    int lane = threadIdx.x & 63;
    int nw = (gridDim.x * blockDim.x) >> 6;
    const int l15 = lane & 15;
    const int grp = lane >> 4;
    const int h = lane >> 3, g = lane & 7;
    for (int node = wid; node < n; node += nw) {
        int start = off[node];
        int deg = (int)cnt[node];
        float a[8];
#pragma unroll
        for (int i = 0; i < 8; ++i) a[i] = 0.f;
        for (int j = 0; j < deg; j += 8) {
            int i0 = j + grp, i1 = j + 4 + grp;
            uint4 u0 = make_uint4(0, 0, 0, 0), u1 = make_uint4(0, 0, 0, 0);
            if (i0 < deg) {
                int b = sortedB[start + i0];
                u0 = *(const uint4*)(qkv + (size_t)b * 384 + 128 + l15 * 8);
            }
            if (i1 < deg) {
                int b = sortedB[start + i1];
                u1 = *(const uint4*)(qkv + (size_t)b * 384 + 128 + l15 * 8);
            }
            unsigned w0[4] = {u0.x, u0.y, u0.z, u0.w};
            unsigned w1[4] = {u1.x, u1.y, u1.z, u1.w};
#pragma unroll
            for (int i = 0; i < 4; ++i) {
                a[2 * i]     += bfbits2f(w0[i] & 0xffffu) + bfbits2f(w1[i] & 0xffffu);
                a[2 * i + 1] += bfbits2f(w0[i] >> 16)     + bfbits2f(w1[i] >> 16);
            }
        }
#pragma unroll
        for (int i = 0; i < 8; ++i) {
            a[i] += __shfl_xor(a[i], 16, 64);
            a[i] += __shfl_xor(a[i], 32, 64);
        }

        const short* qp = qkv + (size_t)node * 384 + h * 16;
        uint4 qa = *(const uint4*)qp;
        uint4 qb = *(const uint4*)(qp + 8);
        float qv[16];
        {
            unsigned ua[4] = {qa.x, qa.y, qa.z, qa.w};
            unsigned ub[4] = {qb.x, qb.y, qb.z, qb.w};
#pragma unroll
            for (int w2 = 0; w2 < 4; ++w2) {
                qv[2 * w2]         = bfbits2f(ua[w2] & 0xffffu);
                qv[2 * w2 + 1]     = bfbits2f(ua[w2] >> 16);
                qv[8 + 2 * w2]     = bfbits2f(ub[w2] & 0xffffu);
                qv[8 + 2 * w2 + 1] = bfbits2f(ub[w2] >> 16);
            }
        }
        float s = 0.f;
#pragma unroll
        for (int i = 0; i < 8; ++i) {
            s += qv[i]     * __shfl(a[i], 2 * g, 64);
            s += qv[8 + i] * __shfl(a[i], 2 * g + 1, 64);
        }
        float c = cntf[node];
        s *= 1.0f / fmaxf(c, 1.0f);
        float m = s;
#pragma unroll
        for (int o = 1; o < 8; o <<= 1) m = fmaxf(m, __shfl_xor(m, o, 64));
        float e = __expf(s - m);
        float sum = e;
#pragma unroll
        for (int o = 1; o < 8; o <<= 1) sum += __shfl_xor(sum, o, 64);
        float p = e / sum;
        float o0 = 0.f, o1 = 0.f;
        int d0 = g * 2;
#pragma unroll
        for (int gg = 0; gg < 8; ++gg) {
            float pg = __shfl(p, h * 8 + gg, 64);
            unsigned vv = *(const unsigned*)(qkv + (size_t)node * 384 + 256 + gg * 16 + d0);
            o0 += pg * bfbits2f(vv & 0xffffu);
            o1 += pg * bfbits2f(vv >> 16);
        }
        unsigned pk = (unsigned)(unsigned short)f2bf(o0) | ((unsigned)(unsigned short)f2bf(o1) << 16);
        *(unsigned*)(attno + (size_t)node * EMB + h * 16 + d0) = pk;
    }
}

// ---------------------------------------------------------------------------
// BatchNorm helpers
// ---------------------------------------------------------------------------
__global__ void bn_finalize_slots(const float* __restrict__ slots, float* __restrict__ scsh,
                                  const float* __restrict__ g, const float* __restrict__ be, int n) {
    int c = threadIdx.x;
    float s = 0.f, q = 0.f;
    for (int i = 0; i < 64; ++i) {
        s += slots[(size_t)i * 256 + c];
        q += slots[(size_t)i * 256 + 128 + c];
    }
    float invn = 1.0f / (float)n;
    float mean = s * invn;
    float var = fmaxf(q * invn - mean * mean, 0.f);
    float sc = g[c] * rsqrtf(var + 1e-5f);
    scsh[c] = sc;
    scsh[128 + c] = be[c] - mean * sc;
}

// xn1 = bf16(bn1(y1)) : read fp32, apply scale/shift, write bf16
__global__ void apply_bn_bf16(const float* __restrict__ Y, const float* __restrict__ scsh,
                              short* __restrict__ out, size_t total8) {
    size_t stride = (size_t)gridDim.x * blockDim.x;
    for (size_t i = (size_t)blockIdx.x * blockDim.x + threadIdx.x; i < total8; i += stride) {
        size_t base = i * 8;
        f4 lo = *(const f4*)(Y + base);
        f4 hi = *(const f4*)(Y + base + 4);
        int c = (int)(base & 127);
        f4 s0 = *(const f4*)(scsh + c);
        f4 s1 = *(const f4*)(scsh + c + 4);
        f4 h0 = *(const f4*)(scsh + 128 + c);
        f4 h1 = *(const f4*)(scsh + 128 + c + 4);
        lo = lo * s0 + h0;
        hi = hi * s1 + h1;
        bh8 o;
        o[0] = f2bf(lo[0]); o[1] = f2bf(lo[1]); o[2] = f2bf(lo[2]); o[3] = f2bf(lo[3]);
        o[4] = f2bf(hi[0]); o[5] = f2bf(hi[1]); o[6] = f2bf(hi[2]); o[7] = f2bf(hi[3]);
        *(bh8*)(out + base) = o;
    }
}

__global__ void bn_apply(float* __restrict__ Y, const float* __restrict__ scsh, size_t total4) {
    size_t stride = (size_t)gridDim.x * blockDim.x;
    for (size_t i = (size_t)blockIdx.x * blockDim.x + threadIdx.x; i < total4; i += stride) {
        f4 vv = ((f4*)Y)[i];
        int c = (int)((i * 4) & 127);
#pragma unroll
        for (int j = 0; j < 4; ++j) vv[j] = vv[j] * scsh[c + j] + scsh[128 + c + j];
        ((f4*)Y)[i] = vv;
    }
}

// ---------------------------------------------------------------------------
extern "C" void kernel_launch(void* const* d_in, const int* in_sizes, int n_in,
                              void* d_out, int out_size, void* d_ws, size_t ws_size,
                              hipStream_t stream) {
    const float* x   = (const float*)d_in[0];
    const float* wq  = (const float*)d_in[1];
    const float* bq  = (const float*)d_in[2];
    const float* wk  = (const float*)d_in[3];
    const float* bk  = (const float*)d_in[4];
    const float* wv  = (const float*)d_in[5];
    const float* bv  = (const float*)d_in[6];
    const float* wo  = (const float*)d_in[7];
    const float* bo  = (const float*)d_in[8];
    const float* w1  = (const float*)d_in[9];
    const float* b1  = (const float*)d_in[10];
    const float* w2  = (const float*)d_in[11];
    const float* b2  = (const float*)d_in[12];
    const float* g1  = (const float*)d_in[13];
    const float* be1 = (const float*)d_in[14];
    const float* g2  = (const float*)d_in[15];
    const float* be2 = (const float*)d_in[16];
    const int* edge  = (const int*)d_in[17];

    int n = in_sizes[0] / EMB;      // 50000
    int E = in_sizes[17] / 2;       // 800000

    // workspace layout (float units)
    float* wsf = (float*)d_ws;
    unsigned* cnt_u = (unsigned*)wsf;                       // 65536
    float*  cntf  = wsf + 65536;                            // 65536
    int*    off   = (int*)(wsf + 2 * 65536);                // 65536
    int*    offw  = (int*)(wsf + 3 * 65536);                // 65536
    int*    bsum  = (int*)(wsf + 4 * 65536);                // 64
    int*    sortedB = (int*)(wsf + 4 * 65536 + 64);         // E
    float*  base5 = wsf + 4 * 65536 + 64 + E;
    short*  qkv   = (short*)base5;                          // n*384 bf16 = n*192 f
    short*  attno = (short*)(base5 + (size_t)n * 256);      // n*128 bf16
    float*  y1    = base5 + (size_t)n * 320;                // n*128 f
    float*  warea = y1 + (size_t)n * 128;
    short*  wqkvT = (short*)warea;                          // 384*128 bf16
    short*  woT   = wqkvT + 384 * 128;                      // 128*128
    short*  w1T   = woT + 128 * 128;                        // 512*128
    short*  w2T   = w1T + 512 * 128;                        // 128*512
    float*  bqkv  = (float*)(w2T + 128 * 512);              // 384
    float*  slots1 = bqkv + 384;                            // 64*256
    float*  slots2 = slots1 + 64 * 256;                     // 64*256
    float*  scsh1  = slots2 + 64 * 256;                     // 256
    float*  scsh2  = scsh1 + 256;                           // 256
    short*  xn1   = attno;                                  // n*128 bf16 (attno dead after wo-GEMM)
    float*  y2    = (float*)d_out;

    hipMemsetAsync(cnt_u, 0, 65536 * sizeof(unsigned), stream);
    hipMemsetAsync(slots1, 0, 2 * 64 * 256 * sizeof(float), stream);

    // edge counting sort
    int nb = (n + 1023) / 1024;  // 49
    hist_kernel<<<2048, 256, 0, stream>>>(edge, cnt_u, E);
    scan_blocks<<<nb, 256, 0, stream>>>(cnt_u, off, bsum, n);
    scan_bsums<<<1, 64, 0, stream>>>(bsum, nb);
    scan_apply<<<nb, 256, 0, stream>>>(cnt_u, bsum, off, offw, cntf, n);
    place_kernel<<<2048, 256, 0, stream>>>(edge, offw, sortedB, E);

    // merged weight prep (6 transposes + bias concat, one launch)
    prep_all<<<768, 256, 0, stream>>>(wq, wk, wv, wo, w1, w2, bq, bk, bv,
                                      wqkvT, woT, w1T, w2T, bqkv);

    int nrb = (n + 127) / 128;              // 391 row-groups
    int nrb8 = ((nrb + 7) / 8) * 8;         // 392, XCD-aligned
    const size_t CSH = 128 * CSTRIDE * sizeof(short);  // 34816 B

    // qkv = x @ [wq|wk|wv] + bqkv  (fp32 in, converted in-reg; bf16 out [n][384])
    mfma_gemm<128, false, false, true, false, false, false><<<nrb8 * 3, 256, CSH, stream>>>(
        x, wqkvT, bqkv, nullptr, qkv, nullptr, n, 384, 3, nrb);

    // fused: ksum gather (in regs, vector loads) + attention -> attno
    gather_attn_kernel<<<6144, 256, 0, stream>>>(qkv, off, cnt_u, sortedB, cntf, attno, n);

    // y1 = attno@wo + bo + x (fp32 out) + fused BN1 stats
    mfma_gemm<128, true, false, false, true, false, true><<<nrb, 256, 0, stream>>>(
        attno, woT, bo, x, y1, slots1, n, EMB, 1, nrb);

    bn_finalize_slots<<<1, 128, 0, stream>>>(slots1, scsh1, g1, be1, n);

    // xn1 = bf16(bn1(y1))  (overwrites attno region; attno is dead)
    apply_bn_bf16<<<1600, 256, 0, stream>>>(y1, scsh1, xn1, (size_t)n * EMB / 8);

    // FUSED FFN: y2 = gelu(xn1@w1+b1)@w2 + b2 + xn1, + BN2 stats
    ffn_fused<<<nrb, 256, CSH, stream>>>(xn1, w1T, b1, w2T, b2, y2, slots2, n);

    bn_finalize_slots<<<1, 128, 0, stream>>>(slots2, scsh2, g2, be2, n);
    bn_apply<<<512, 256, 0, stream>>>(y2, scsh2, (size_t)n * EMB / 4);
}

// Round 22
// 287.894 us; speedup vs baseline: 1.1228x; 1.0452x over previous
//
#include <hip/hip_runtime.h>
#include <hip/hip_bf16.h>

typedef float f4 __attribute__((ext_vector_type(4)));
typedef short bh8 __attribute__((ext_vector_type(8)));   // 8 bf16 (4 VGPRs)

#define EMB 128
#define HID 512

__device__ __forceinline__ float bfbits2f(unsigned int lo16) {
    unsigned int u = lo16 << 16;
    return __builtin_bit_cast(float, u);
}
__device__ __forceinline__ short f2bf(float f) {
    __hip_bfloat16 h = __float2bfloat16(f);
    return __builtin_bit_cast(short, h);
}
// fast GELU: x*sigmoid(1.5957691x + 0.0713548x^3); |err vs erf-GELU| <~1e-3,
// below the bf16 rounding applied to h.
__device__ __forceinline__ float gelu_fast(float x) {
    float x3 = x * x * x;
    float y = 1.5957691216f * x + 0.0713548163f * x3;
    return x / (1.0f + __expf(-y));
}

// ---------------------------------------------------------------------------
// Counting sort of edges by destination A. (place is fused into the qkv GEMM)
// ---------------------------------------------------------------------------
__global__ void hist_kernel(const int* __restrict__ edge, unsigned* __restrict__ cnt, int E) {
    int stride = gridDim.x * blockDim.x;
    for (int e = blockIdx.x * blockDim.x + threadIdx.x; e < E; e += stride)
        atomicAdd(&cnt[edge[e]], 1u);
}

__global__ void scan_blocks(const unsigned* __restrict__ cnt, int* __restrict__ off,
                            int* __restrict__ bsum, int n) {
    __shared__ int ls[256];
    int tid = threadIdx.x;
    int base = blockIdx.x * 1024 + tid * 4;
    int v0 = 0, v1 = 0, v2 = 0, v3 = 0;
    if (base + 0 < n) v0 = (int)cnt[base + 0];
    if (base + 1 < n) v1 = (int)cnt[base + 1];
    if (base + 2 < n) v2 = (int)cnt[base + 2];
    if (base + 3 < n) v3 = (int)cnt[base + 3];
    int s = v0 + v1 + v2 + v3;
    ls[tid] = s;
    __syncthreads();
    for (int d = 1; d < 256; d <<= 1) {
        int t = (tid >= d) ? ls[tid - d] : 0;
        __syncthreads();
        ls[tid] += t;
        __syncthreads();
    }
    int incl = ls[tid];
    int run = incl - s;
    if (tid == 255) bsum[blockIdx.x] = incl;
    if (base + 0 < n) { off[base + 0] = run; run += v0; }
    if (base + 1 < n) { off[base + 1] = run; run += v1; }
    if (base + 2 < n) { off[base + 2] = run; run += v2; }
    if (base + 3 < n) { off[base + 3] = run; }
}

__global__ void scan_bsums(int* __restrict__ bsum, int nb) {
    int lane = threadIdx.x & 63;
    int x = (lane < nb) ? bsum[lane] : 0;
    int orig = x;
#pragma unroll
    for (int o = 1; o < 64; o <<= 1) {
        int t = __shfl_up(x, o, 64);
        if (lane >= o) x += t;
    }
    if (lane < nb) bsum[lane] = x - orig;
}

__global__ void scan_apply(const unsigned* __restrict__ cnt, const int* __restrict__ bsum,
                           int* __restrict__ off, int* __restrict__ offw,
                           float* __restrict__ cntf, int n) {
    int base = blockIdx.x * 1024 + threadIdx.x * 4;
    int add = bsum[blockIdx.x];
#pragma unroll
    for (int i = 0; i < 4; ++i) {
        int idx = base + i;
        if (idx < n) {
            int o = off[idx] + add;
            off[idx] = o;
            offw[idx] = o;
            cntf[idx] = (float)cnt[idx];
        }
    }
}

// ---------------------------------------------------------------------------
// Merged weight prep: all 6 transposes + bias concat in ONE launch.
// ---------------------------------------------------------------------------
__global__ void prep_all(const float* __restrict__ wq, const float* __restrict__ wk,
                         const float* __restrict__ wv, const float* __restrict__ wo,
                         const float* __restrict__ w1, const float* __restrict__ w2,
                         const float* __restrict__ bq, const float* __restrict__ bk,
                         const float* __restrict__ bv,
                         short* __restrict__ wqkvT, short* __restrict__ woT,
                         short* __restrict__ w1T, short* __restrict__ w2T,
                         float* __restrict__ bqkv) {
    int id = blockIdx.x * blockDim.x + threadIdx.x;
    if (id < 16384) {
        int k = id >> 7, c = id & 127;
        wqkvT[c * 128 + k] = f2bf(wq[id]);
    } else if (id < 32768) {
        int t = id - 16384; int k = t >> 7, c = t & 127;
        wqkvT[(128 + c) * 128 + k] = f2bf(wk[t]);
    } else if (id < 49152) {
        int t = id - 32768; int k = t >> 7, c = t & 127;
        wqkvT[(256 + c) * 128 + k] = f2bf(wv[t]);
    } else if (id < 65536) {
        int t = id - 49152; int k = t >> 7, c = t & 127;
        woT[c * 128 + k] = f2bf(wo[t]);
    } else if (id < 131072) {
        int t = id - 65536; int k = t >> 9, c = t & 511;
        w1T[c * 128 + k] = f2bf(w1[t]);
    } else if (id < 196608) {
        int t = id - 131072; int k = t >> 7, c = t & 127;
        w2T[c * 512 + k] = f2bf(w2[t]);
    }
    if (id < 128) {
        bqkv[id] = bq[id];
        bqkv[128 + id] = bk[id];
        bqkv[256 + id] = bv[id];
    }
}

// ---------------------------------------------------------------------------
// Fragment loader for one k-step (32 cols): 4 A frags + 4 B frags.
// ---------------------------------------------------------------------------
template<int KT, bool IN_BF16>
__device__ __forceinline__ void ld_ab(bh8 (&av)[4], bh8 (&bv)[4],
                                      const float* __restrict__ Xf, const short* __restrict__ Xb,
                                      const int (&rowA)[4], const short* __restrict__ Wt,
                                      int C0, int l15, int kbase) {
#pragma unroll
    for (int rf = 0; rf < 4; ++rf) {
        if constexpr (IN_BF16) {
            av[rf] = *(const bh8*)(Xb + (size_t)rowA[rf] * KT + kbase);
        } else {
            f4 lo = *(const f4*)(Xf + (size_t)rowA[rf] * KT + kbase);
            f4 hi = *(const f4*)(Xf + (size_t)rowA[rf] * KT + kbase + 4);
            bh8 t;
            t[0] = f2bf(lo[0]); t[1] = f2bf(lo[1]); t[2] = f2bf(lo[2]); t[3] = f2bf(lo[3]);
            t[4] = f2bf(hi[0]); t[5] = f2bf(hi[1]); t[6] = f2bf(hi[2]); t[7] = f2bf(hi[3]);
            av[rf] = t;
        }
    }
#pragma unroll
    for (int cf = 0; cf < 4; ++cf)
        bv[cf] = *(const bh8*)(Wt + (size_t)(C0 + cf * 16 + l15) * KT + kbase);
}

__device__ __forceinline__ void mm16(f4 (&acc)[4][4], const bh8 (&av)[4], const bh8 (&bv)[4]) {
#pragma unroll
    for (int rf = 0; rf < 4; ++rf)
#pragma unroll
        for (int cf = 0; cf < 4; ++cf)
            acc[rf][cf] = __builtin_amdgcn_mfma_f32_16x16x32_bf16(av[rf], bv[cf], acc[rf][cf], 0, 0, 0);
}

// ---------------------------------------------------------------------------
// MFMA GEMM (qkv / wo): 256 threads = 2x2 waves; 128x128 per block.
// 2-deep ping-pong K-pipeline. XCD-aware panel placement.
// PLACE: grid-union fusion — blocks past gemmBlocks run the (data-independent)
// edge scatter (counting-sort placement) instead; they fill issue slots the
// latency-bound GEMM leaves idle, overlapping two serial ~50us kernels.
// ---------------------------------------------------------------------------
#define CSTRIDE 136   // shorts; 272B row stride: 16B-aligned, breaks kg bank aliasing

template<int KT, bool IN_BF16, bool GELU, bool OUT_BF16, bool RESID, bool RBF16, bool STATS, bool PLACE>
__global__ __launch_bounds__(256, 2) void mfma_gemm(
    const void* __restrict__ Xv, const short* __restrict__ Wt, const float* __restrict__ bias,
    const void* __restrict__ resid,
    void* __restrict__ outv, float* __restrict__ slots, int n, int OC, int ncolb, int nrb,
    const int* __restrict__ edge, int* __restrict__ offw, int* __restrict__ sortedB,
    int E, int gemmBlocks)
{
    if constexpr (PLACE) {
        if ((int)blockIdx.x >= gemmBlocks) {
            int tid0 = (blockIdx.x - gemmBlocks) * 256 + threadIdx.x;
            int stride = (gridDim.x - gemmBlocks) * 256;
            for (int e = tid0; e < E; e += stride) {
                int a = edge[e];
                int pos = atomicAdd(&offw[a], 1);
                sortedB[pos] = edge[E + e];
            }
            return;
        }
    }
    int bx, by;
    if (ncolb == 1) {
        bx = blockIdx.x; by = 0;
    } else {
        int q = blockIdx.x >> 3;
        by = q % ncolb;
        bx = (q / ncolb) * 8 + (blockIdx.x & 7);
        if (bx >= nrb) return;
    }
    const int lane = threadIdx.x & 63;
    const int w = threadIdx.x >> 6;
    const int wr = w >> 1, wc = w & 1;
    const int R0 = bx * 128 + wr * 64;
    const int C0 = by * 128 + wc * 64;
    const int l15 = lane & 15;
    const int kg = lane >> 4;

    const float* Xf = (const float*)Xv;
    const short* Xb = (const short*)Xv;

    int rowA[4];
#pragma unroll
    for (int rf = 0; rf < 4; ++rf) rowA[rf] = min(R0 + rf * 16 + l15, n - 1);

    f4 acc[4][4];
#pragma unroll
    for (int rf = 0; rf < 4; ++rf)
#pragma unroll
        for (int cf = 0; cf < 4; ++cf) acc[rf][cf] = 0.f;

    constexpr int NT = KT / 32;
    bh8 aA[4], bA[4], aB[4], bB[4];

    ld_ab<KT, IN_BF16>(aA, bA, Xf, Xb, rowA, Wt, C0, l15, kg * 8);
#pragma unroll
    for (int t = 0; t < NT; t += 2) {
        ld_ab<KT, IN_BF16>(aB, bB, Xf, Xb, rowA, Wt, C0, l15, (t + 1) * 32 + kg * 8);
        mm16(acc, aA, bA);
        if (t + 2 < NT)
            ld_ab<KT, IN_BF16>(aA, bA, Xf, Xb, rowA, Wt, C0, l15, (t + 2) * 32 + kg * 8);
        mm16(acc, aB, bB);
    }

    if constexpr (OUT_BF16) {
        extern __shared__ short cs[];
        const int lrb = wr * 64;
        const int lcb = wc * 64;
#pragma unroll
        for (int cf = 0; cf < 4; ++cf) {
            const float bcol = bias[C0 + cf * 16 + l15];
#pragma unroll
            for (int rf = 0; rf < 4; ++rf) {
#pragma unroll
                for (int i = 0; i < 4; ++i) {
                    float val = acc[rf][cf][i] + bcol;
                    if constexpr (GELU) val = gelu_fast(val);
                    cs[(lrb + rf * 16 + kg * 4 + i) * CSTRIDE + lcb + cf * 16 + l15] = f2bf(val);
                }
            }
        }
        __syncthreads();
        const int tc = threadIdx.x & 15;
        const int tr = threadIdx.x >> 4;
        const int gcb = by * 128;
#pragma unroll
        for (int r = 0; r < 8; ++r) {
            int lrow = tr + r * 16;
            int grow = bx * 128 + lrow;
            if (grow < n) {
                bh8 v = *(bh8*)(cs + lrow * CSTRIDE + tc * 8);
                *(bh8*)((short*)outv + (size_t)grow * OC + gcb + tc * 8) = v;
            }
        }
    } else {
#pragma unroll
        for (int cf = 0; cf < 4; ++cf) {
            const int col = C0 + cf * 16 + l15;
            const float bcol = bias[col];
#pragma unroll
            for (int rf = 0; rf < 4; ++rf) {
                float s = 0.f, q = 0.f;
#pragma unroll
                for (int i = 0; i < 4; ++i) {
                    const int row = R0 + rf * 16 + kg * 4 + i;
                    if (row < n) {
                        float val = acc[rf][cf][i] + bcol;
                        if constexpr (RESID) {
                            float rv;
                            if constexpr (RBF16)
                                rv = bfbits2f((unsigned short)((const short*)resid)[(size_t)row * EMB + col]);
                            else
                                rv = ((const float*)resid)[(size_t)row * EMB + col];
                            val += rv;
                        }
                        if constexpr (GELU) val = gelu_fast(val);
                        if constexpr (STATS) { s += val; q += val * val; }
                        ((float*)outv)[(size_t)row * OC + col] = val;
                    }
                }
                if constexpr (STATS) {
                    s += __shfl_xor(s, 16, 64); s += __shfl_xor(s, 32, 64);
                    q += __shfl_xor(q, 16, 64); q += __shfl_xor(q, 32, 64);
                    if (kg == 0) {
                        float* sl = slots + (size_t)(bx & 63) * 256;
                        unsafeAtomicAdd(&sl[col], s);
                        unsafeAtomicAdd(&sl[128 + col], q);
                    }
                }
            }
        }
    }
}

// ---------------------------------------------------------------------------
// FUSED FFN (round-16 structure, best of 4 variants) + BN1-apply folded in:
// y2 = gelu(bn1(y1)@w1+b1)@w2 + b2 + bn1(y1), fused BN2 stats.
// bn1(y1) is computed in-register from y1 fp32 + scsh1 (A-frags bf16-rounded
// identically to the old xn1 buffer; residual now fp32-exact). This deletes
// the apply_bn_bf16 kernel + xn1 buffer entirely. Chunk loop / pipeline /
// barriers unchanged (r17 & r19 restructurings both regressed).
// ---------------------------------------------------------------------------
__global__ __launch_bounds__(256, 2) void ffn_fused(
    const float* __restrict__ y1, const float* __restrict__ scsh1,
    const short* __restrict__ w1T, const float* __restrict__ b1,
    const short* __restrict__ w2T, const float* __restrict__ b2,
    float* __restrict__ y2, float* __restrict__ slots, int n)
{
    extern __shared__ short hs[];   // [128][CSTRIDE] bf16
    const int bx = blockIdx.x;
    const int lane = threadIdx.x & 63;
    const int w = threadIdx.x >> 6;
    const int wr = w >> 1, wc = w & 1;
    const int R0 = bx * 128 + wr * 64;
    const int l15 = lane & 15;
    const int kg = lane >> 4;

    int rowA[4];
#pragma unroll
    for (int rf = 0; rf < 4; ++rf) rowA[rf] = min(R0 + rf * 16 + l15, n - 1);

    // hoisted bn1(y1) A-fragments (in-reg BN apply + bf16 convert)
    bh8 aF0[4], aF1[4], aF2[4], aF3[4];
#pragma unroll
    for (int seg = 0; seg < 4; ++seg) {
        const int kb = seg * 32 + kg * 8;
        f4 s0 = *(const f4*)(scsh1 + kb);
        f4 s1 = *(const f4*)(scsh1 + kb + 4);
        f4 h0 = *(const f4*)(scsh1 + 128 + kb);
        f4 h1 = *(const f4*)(scsh1 + 128 + kb + 4);
#pragma unroll
        for (int rf = 0; rf < 4; ++rf) {
            const float* p = y1 + (size_t)rowA[rf] * EMB + kb;
            f4 lo = *(const f4*)(p);
            f4 hi = *(const f4*)(p + 4);
            lo = lo * s0 + h0;
            hi = hi * s1 + h1;
            bh8 t;
            t[0] = f2bf(lo[0]); t[1] = f2bf(lo[1]); t[2] = f2bf(lo[2]); t[3] = f2bf(lo[3]);
            t[4] = f2bf(hi[0]); t[5] = f2bf(hi[1]); t[6] = f2bf(hi[2]); t[7] = f2bf(hi[3]);
            if (seg == 0) aF0[rf] = t;
            else if (seg == 1) aF1[rf] = t;
            else if (seg == 2) aF2[rf] = t;
            else aF3[rf] = t;
        }
    }

    f4 acc2[4][4];
#pragma unroll
    for (int rf = 0; rf < 4; ++rf)
#pragma unroll
        for (int cf = 0; cf < 4; ++cf) acc2[rf][cf] = 0.f;

    const int lrb = wr * 64;
    const int lcb = wc * 64;

    for (int c = 0; c < 4; ++c) {
        // ---- FC1 chunk: acc1 = bn1(y1) @ w1T[cols c*128+wc*64 .. +63] ----
        f4 acc1[4][4];
#pragma unroll
        for (int rf = 0; rf < 4; ++rf)
#pragma unroll
            for (int cf = 0; cf < 4; ++cf) acc1[rf][cf] = 0.f;

        bh8 bP[4], bQ[4];
        auto ldB1 = [&](bh8 (&dst)[4], int ks) {
#pragma unroll
            for (int cf = 0; cf < 4; ++cf) {
                int col = c * 128 + wc * 64 + cf * 16 + l15;
                dst[cf] = *(const bh8*)(w1T + (size_t)col * EMB + ks * 32 + kg * 8);
            }
        };
        ldB1(bP, 0);
        ldB1(bQ, 1);
        mm16(acc1, aF0, bP);
        ldB1(bP, 2);
        mm16(acc1, aF1, bQ);
        ldB1(bQ, 3);
        mm16(acc1, aF2, bP);
        mm16(acc1, aF3, bQ);

        // ---- fast GELU -> LDS tile ----
        __syncthreads();   // protect previous chunk's LDS reads
#pragma unroll
        for (int cf = 0; cf < 4; ++cf) {
            const float bcol = b1[c * 128 + wc * 64 + cf * 16 + l15];
#pragma unroll
            for (int rf = 0; rf < 4; ++rf) {
#pragma unroll
                for (int i = 0; i < 4; ++i) {
                    float val = gelu_fast(acc1[rf][cf][i] + bcol);
                    hs[(lrb + rf * 16 + kg * 4 + i) * CSTRIDE + lcb + cf * 16 + l15] = f2bf(val);
                }
            }
        }
        __syncthreads();

        // ---- FC2 partial: acc2 += h_chunk @ w2T[:, c*128..] ----
        bh8 aP[4], aQ[4];
        auto ldA2 = [&](bh8 (&dst)[4], int ks) {
#pragma unroll
            for (int rf = 0; rf < 4; ++rf)
                dst[rf] = *(const bh8*)(hs + (wr * 64 + rf * 16 + l15) * CSTRIDE + ks * 32 + kg * 8);
        };
        auto ldB2 = [&](bh8 (&dst)[4], int ks) {
#pragma unroll
            for (int cf = 0; cf < 4; ++cf) {
                int col = wc * 64 + cf * 16 + l15;
                dst[cf] = *(const bh8*)(w2T + (size_t)col * HID + c * 128 + ks * 32 + kg * 8);
            }
        };
        ldA2(aP, 0); ldB2(bP, 0);
        ldA2(aQ, 1); ldB2(bQ, 1);
        mm16(acc2, aP, bP);
        ldA2(aP, 2); ldB2(bP, 2);
        mm16(acc2, aQ, bQ);
        ldA2(aQ, 3); ldB2(bQ, 3);
        mm16(acc2, aP, bP);
        mm16(acc2, aQ, bQ);
    }

    // ---- epilogue: y2 = acc2 + b2 + bn1(y1) (fp32 resid), fused BN2 stats ----
    const int C0 = wc * 64;
#pragma unroll
    for (int cf = 0; cf < 4; ++cf) {
        const int col = C0 + cf * 16 + l15;
        const float bcol = b2[col];
        const float scv = scsh1[col];
        const float shv = scsh1[128 + col];
#pragma unroll
        for (int rf = 0; rf < 4; ++rf) {
            float s = 0.f, q = 0.f;
#pragma unroll
            for (int i = 0; i < 4; ++i) {
                const int row = R0 + rf * 16 + kg * 4 + i;
                if (row < n) {
                    float val = acc2[rf][cf][i] + bcol;
                    val += y1[(size_t)row * EMB + col] * scv + shv;
                    s += val; q += val * val;
                    y2[(size_t)row * EMB + col] = val;
                }
            }
            s += __shfl_xor(s, 16, 64); s += __shfl_xor(s, 32, 64);
            q += __shfl_xor(q, 16, 64); q += __shfl_xor(q, 32, 64);
            if (kg == 0) {
                float* sl = slots + (size_t)(bx & 63) * 256;
                unsafeAtomicAdd(&sl[col], s);
                unsafeAtomicAdd(&sl[128 + col], q);
            }
        }
    }
}

// ---------------------------------------------------------------------------
// FUSED gather+attention (round-14 vector-load version).
// ---------------------------------------------------------------------------
__global__ void gather_attn_kernel(const short* __restrict__ qkv, const int* __restrict__ off,
                                   const unsigned* __restrict__ cnt, const int* __restrict__ sortedB,
                                   const float* __restrict__ cntf, short* __restrict__ attno, int n) {
    int wid = (int)((blockIdx.x * blockDim.x + threadIdx.x) >> 6);
    int lane = threadIdx.x & 63;
    int nw = (gridDim.x * blockDim.x) >> 6;
    const int l15 = lane & 15;
    const int grp = lane >> 4;
    const int h = lane >> 3, g = lane & 7;
    for (int node = wid; node < n; node += nw) {
        int start = off[node];
        int deg = (int)cnt[node];
        float a[8];
#pragma unroll
        for (int i = 0; i < 8; ++i) a[i] = 0.f;
        for (int j = 0; j < deg; j += 8) {
            int i0 = j + grp, i1 = j + 4 + grp;
            uint4 u0 = make_uint4(0, 0, 0, 0), u1 = make_uint4(0, 0, 0, 0);
            if (i0 < deg) {
                int b = sortedB[start + i0];
                u0 = *(const uint4*)(qkv + (size_t)b * 384 + 128 + l15 * 8);
            }
            if (i1 < deg) {
                int b = sortedB[start + i1];
                u1 = *(const uint4*)(qkv + (size_t)b * 384 + 128 + l15 * 8);
            }
            unsigned w0[4] = {u0.x, u0.y, u0.z, u0.w};
            unsigned w1[4] = {u1.x, u1.y, u1.z, u1.w};
#pragma unroll
            for (int i = 0; i < 4; ++i) {
                a[2 * i]     += bfbits2f(w0[i] & 0xffffu) + bfbits2f(w1[i] & 0xffffu);
                a[2 * i + 1] += bfbits2f(w0[i] >> 16)     + bfbits2f(w1[i] >> 16);
            }
        }
#pragma unroll
        for (int i = 0; i < 8; ++i) {
            a[i] += __shfl_xor(a[i], 16, 64);
            a[i] += __shfl_xor(a[i], 32, 64);
        }

        const short* qp = qkv + (size_t)node * 384 + h * 16;
        uint4 qa = *(const uint4*)qp;
        uint4 qb = *(const uint4*)(qp + 8);
        float qv[16];
        {
            unsigned ua[4] = {qa.x, qa.y, qa.z, qa.w};
            unsigned ub[4] = {qb.x, qb.y, qb.z, qb.w};
#pragma unroll
            for (int w2 = 0; w2 < 4; ++w2) {
                qv[2 * w2]         = bfbits2f(ua[w2] & 0xffffu);
                qv[2 * w2 + 1]     = bfbits2f(ua[w2] >> 16);
                qv[8 + 2 * w2]     = bfbits2f(ub[w2] & 0xffffu);
                qv[8 + 2 * w2 + 1] = bfbits2f(ub[w2] >> 16);
            }
        }
        float s = 0.f;
#pragma unroll
        for (int i = 0; i < 8; ++i) {
            s += qv[i]     * __shfl(a[i], 2 * g, 64);
            s += qv[8 + i] * __shfl(a[i], 2 * g + 1, 64);
        }
        float c = cntf[node];
        s *= 1.0f / fmaxf(c, 1.0f);
        float m = s;
#pragma unroll
        for (int o = 1; o < 8; o <<= 1) m = fmaxf(m, __shfl_xor(m, o, 64));
        float e = __expf(s - m);
        float sum = e;
#pragma unroll
        for (int o = 1; o < 8; o <<= 1) sum += __shfl_xor(sum, o, 64);
        float p = e / sum;
        float o0 = 0.f, o1 = 0.f;
        int d0 = g * 2;
#pragma unroll
        for (int gg = 0; gg < 8; ++gg) {
            float pg = __shfl(p, h * 8 + gg, 64);
            unsigned vv = *(const unsigned*)(qkv + (size_t)node * 384 + 256 + gg * 16 + d0);
            o0 += pg * bfbits2f(vv & 0xffffu);
            o1 += pg * bfbits2f(vv >> 16);
        }
        unsigned pk = (unsigned)(unsigned short)f2bf(o0) | ((unsigned)(unsigned short)f2bf(o1) << 16);
        *(unsigned*)(attno + (size_t)node * EMB + h * 16 + d0) = pk;
    }
}

// ---------------------------------------------------------------------------
// BatchNorm helpers
// ---------------------------------------------------------------------------
__global__ void bn_finalize_slots(const float* __restrict__ slots, float* __restrict__ scsh,
                                  const float* __restrict__ g, const float* __restrict__ be, int n) {
    int c = threadIdx.x;
    float s = 0.f, q = 0.f;
    for (int i = 0; i < 64; ++i) {
        s += slots[(size_t)i * 256 + c];
        q += slots[(size_t)i * 256 + 128 + c];
    }
    float invn = 1.0f / (float)n;
    float mean = s * invn;
    float var = fmaxf(q * invn - mean * mean, 0.f);
    float sc = g[c] * rsqrtf(var + 1e-5f);
    scsh[c] = sc;
    scsh[128 + c] = be[c] - mean * sc;
}

__global__ void bn_apply(float* __restrict__ Y, const float* __restrict__ scsh, size_t total4) {
    size_t stride = (size_t)gridDim.x * blockDim.x;
    for (size_t i = (size_t)blockIdx.x * blockDim.x + threadIdx.x; i < total4; i += stride) {
        f4 vv = ((f4*)Y)[i];
        int c = (int)((i * 4) & 127);
#pragma unroll
        for (int j = 0; j < 4; ++j) vv[j] = vv[j] * scsh[c + j] + scsh[128 + c + j];
        ((f4*)Y)[i] = vv;
    }
}

// ---------------------------------------------------------------------------
extern "C" void kernel_launch(void* const* d_in, const int* in_sizes, int n_in,
                              void* d_out, int out_size, void* d_ws, size_t ws_size,
                              hipStream_t stream) {
    const float* x   = (const float*)d_in[0];
    const float* wq  = (const float*)d_in[1];
    const float* bq  = (const float*)d_in[2];
    const float* wk  = (const float*)d_in[3];
    const float* bk  = (const float*)d_in[4];
    const float* wv  = (const float*)d_in[5];
    const float* bv  = (const float*)d_in[6];
    const float* wo  = (const float*)d_in[7];
    const float* bo  = (const float*)d_in[8];
    const float* w1  = (const float*)d_in[9];
    const float* b1  = (const float*)d_in[10];
    const float* w2  = (const float*)d_in[11];
    const float* b2  = (const float*)d_in[12];
    const float* g1  = (const float*)d_in[13];
    const float* be1 = (const float*)d_in[14];
    const float* g2  = (const float*)d_in[15];
    const float* be2 = (const float*)d_in[16];
    const int* edge  = (const int*)d_in[17];

    int n = in_sizes[0] / EMB;      // 50000
    int E = in_sizes[17] / 2;       // 800000

    // workspace layout (float units)
    float* wsf = (float*)d_ws;
    unsigned* cnt_u = (unsigned*)wsf;                       // 65536
    float*  cntf  = wsf + 65536;                            // 65536
    int*    off   = (int*)(wsf + 2 * 65536);                // 65536
    int*    offw  = (int*)(wsf + 3 * 65536);                // 65536
    int*    bsum  = (int*)(wsf + 4 * 65536);                // 64
    int*    sortedB = (int*)(wsf + 4 * 65536 + 64);         // E
    float*  base5 = wsf + 4 * 65536 + 64 + E;
    short*  qkv   = (short*)base5;                          // n*384 bf16 = n*192 f
    short*  attno = (short*)(base5 + (size_t)n * 256);      // n*128 bf16
    float*  y1    = base5 + (size_t)n * 320;                // n*128 f
    float*  warea = y1 + (size_t)n * 128;
    short*  wqkvT = (short*)warea;                          // 384*128 bf16
    short*  woT   = wqkvT + 384 * 128;                      // 128*128
    short*  w1T   = woT + 128 * 128;                        // 512*128
    short*  w2T   = w1T + 512 * 128;                        // 128*512
    float*  bqkv  = (float*)(w2T + 128 * 512);              // 384
    float*  slots1 = bqkv + 384;                            // 64*256
    float*  slots2 = slots1 + 64 * 256;                     // 64*256
    float*  scsh1  = slots2 + 64 * 256;                     // 256
    float*  scsh2  = scsh1 + 256;                           // 256
    float*  y2    = (float*)d_out;

    hipMemsetAsync(cnt_u, 0, 65536 * sizeof(unsigned), stream);
    hipMemsetAsync(slots1, 0, 2 * 64 * 256 * sizeof(float), stream);

    // edge counting sort: hist + scan here; placement fused into qkv GEMM
    int nb = (n + 1023) / 1024;  // 49
    hist_kernel<<<2048, 256, 0, stream>>>(edge, cnt_u, E);
    scan_blocks<<<nb, 256, 0, stream>>>(cnt_u, off, bsum, n);
    scan_bsums<<<1, 64, 0, stream>>>(bsum, nb);
    scan_apply<<<nb, 256, 0, stream>>>(cnt_u, bsum, off, offw, cntf, n);

    // merged weight prep (6 transposes + bias concat, one launch)
    prep_all<<<768, 256, 0, stream>>>(wq, wk, wv, wo, w1, w2, bq, bk, bv,
                                      wqkvT, woT, w1T, w2T, bqkv);

    int nrb = (n + 127) / 128;              // 391 row-groups
    int nrb8 = ((nrb + 7) / 8) * 8;         // 392, XCD-aligned
    const size_t CSH = 128 * CSTRIDE * sizeof(short);  // 34816 B
    const int PLACE_BLK = 1024;

    // qkv = x @ [wq|wk|wv] + bqkv (bf16 out [n][384]) FUSED with edge placement
    mfma_gemm<128, false, false, true, false, false, false, true>
        <<<nrb8 * 3 + PLACE_BLK, 256, CSH, stream>>>(
        x, wqkvT, bqkv, nullptr, qkv, nullptr, n, 384, 3, nrb,
        edge, offw, sortedB, E, nrb8 * 3);

    // fused: ksum gather (in regs, vector loads) + attention -> attno
    gather_attn_kernel<<<6144, 256, 0, stream>>>(qkv, off, cnt_u, sortedB, cntf, attno, n);

    // y1 = attno@wo + bo + x (fp32 out) + fused BN1 stats
    mfma_gemm<128, true, false, false, true, false, true, false><<<nrb, 256, 0, stream>>>(
        attno, woT, bo, x, y1, slots1, n, EMB, 1, nrb,
        nullptr, nullptr, nullptr, 0, 0);

    bn_finalize_slots<<<1, 128, 0, stream>>>(slots1, scsh1, g1, be1, n);

    // FUSED FFN (BN1-apply folded in): y2 = gelu(bn1(y1)@w1+b1)@w2 + b2 + bn1(y1)
    ffn_fused<<<nrb, 256, CSH, stream>>>(y1, scsh1, w1T, b1, w2T, b2, y2, slots2, n);

    bn_finalize_slots<<<1, 128, 0, stream>>>(slots2, scsh2, g2, be2, n);
    bn_apply<<<512, 256, 0, stream>>>(y2, scsh2, (size_t)n * EMB / 4);
}

// Round 23
// 270.406 us; speedup vs baseline: 1.1954x; 1.0647x over previous
//
#include <hip/hip_runtime.h>
#include <hip/hip_bf16.h>

typedef float f4 __attribute__((ext_vector_type(4)));
typedef short bh8 __attribute__((ext_vector_type(8)));   // 8 bf16 (4 VGPRs)

#define EMB 128
#define HID 512

__device__ __forceinline__ float bfbits2f(unsigned int lo16) {
    unsigned int u = lo16 << 16;
    return __builtin_bit_cast(float, u);
}
__device__ __forceinline__ short f2bf(float f) {
    __hip_bfloat16 h = __float2bfloat16(f);
    return __builtin_bit_cast(short, h);
}
// fast GELU: x*sigmoid(1.5957691x + 0.0713548x^3); |err vs erf-GELU| <~1e-3,
// below the bf16 rounding applied to h.
__device__ __forceinline__ float gelu_fast(float x) {
    float x3 = x * x * x;
    float y = 1.5957691216f * x + 0.0713548163f * x3;
    return x / (1.0f + __expf(-y));
}

// ---------------------------------------------------------------------------
// Edge counting sort pieces. hist is fused into prep_all; place into qkv GEMM.
// ---------------------------------------------------------------------------
__global__ void scan_blocks(const unsigned* __restrict__ cnt, int* __restrict__ off,
                            int* __restrict__ bsum, int n) {
    __shared__ int ls[256];
    int tid = threadIdx.x;
    int base = blockIdx.x * 1024 + tid * 4;
    int v0 = 0, v1 = 0, v2 = 0, v3 = 0;
    if (base + 0 < n) v0 = (int)cnt[base + 0];
    if (base + 1 < n) v1 = (int)cnt[base + 1];
    if (base + 2 < n) v2 = (int)cnt[base + 2];
    if (base + 3 < n) v3 = (int)cnt[base + 3];
    int s = v0 + v1 + v2 + v3;
    ls[tid] = s;
    __syncthreads();
    for (int d = 1; d < 256; d <<= 1) {
        int t = (tid >= d) ? ls[tid - d] : 0;
        __syncthreads();
        ls[tid] += t;
        __syncthreads();
    }
    int incl = ls[tid];
    int run = incl - s;
    if (tid == 255) bsum[blockIdx.x] = incl;
    if (base + 0 < n) { off[base + 0] = run; run += v0; }
    if (base + 1 < n) { off[base + 1] = run; run += v1; }
    if (base + 2 < n) { off[base + 2] = run; run += v2; }
    if (base + 3 < n) { off[base + 3] = run; }
}

__global__ void scan_bsums(int* __restrict__ bsum, int nb) {
    int lane = threadIdx.x & 63;
    int x = (lane < nb) ? bsum[lane] : 0;
    int orig = x;
#pragma unroll
    for (int o = 1; o < 64; o <<= 1) {
        int t = __shfl_up(x, o, 64);
        if (lane >= o) x += t;
    }
    if (lane < nb) bsum[lane] = x - orig;
}

__global__ void scan_apply(const unsigned* __restrict__ cnt, const int* __restrict__ bsum,
                           int* __restrict__ off, int* __restrict__ offw,
                           float* __restrict__ cntf, int n) {
    int base = blockIdx.x * 1024 + threadIdx.x * 4;
    int add = bsum[blockIdx.x];
#pragma unroll
    for (int i = 0; i < 4; ++i) {
        int idx = base + i;
        if (idx < n) {
            int o = off[idx] + add;
            off[idx] = o;
            offw[idx] = o;
            cntf[idx] = (float)cnt[idx];
        }
    }
}

// ---------------------------------------------------------------------------
// Merged weight prep + FUSED edge histogram (grid union; data-independent).
// Blocks >= prepBlocks run the hist grid-stride loop.
// ---------------------------------------------------------------------------
__global__ void prep_all(const float* __restrict__ wq, const float* __restrict__ wk,
                         const float* __restrict__ wv, const float* __restrict__ wo,
                         const float* __restrict__ w1, const float* __restrict__ w2,
                         const float* __restrict__ bq, const float* __restrict__ bk,
                         const float* __restrict__ bv,
                         short* __restrict__ wqkvT, short* __restrict__ woT,
                         short* __restrict__ w1T, short* __restrict__ w2T,
                         float* __restrict__ bqkv,
                         const int* __restrict__ edge, unsigned* __restrict__ cnt,
                         int E, int prepBlocks) {
    if ((int)blockIdx.x >= prepBlocks) {
        int t0 = (blockIdx.x - prepBlocks) * 256 + threadIdx.x;
        int stride = (gridDim.x - prepBlocks) * 256;
        for (int e = t0; e < E; e += stride)
            atomicAdd(&cnt[edge[e]], 1u);
        return;
    }
    int id = blockIdx.x * blockDim.x + threadIdx.x;
    if (id < 16384) {
        int k = id >> 7, c = id & 127;
        wqkvT[c * 128 + k] = f2bf(wq[id]);
    } else if (id < 32768) {
        int t = id - 16384; int k = t >> 7, c = t & 127;
        wqkvT[(128 + c) * 128 + k] = f2bf(wk[t]);
    } else if (id < 49152) {
        int t = id - 32768; int k = t >> 7, c = t & 127;
        wqkvT[(256 + c) * 128 + k] = f2bf(wv[t]);
    } else if (id < 65536) {
        int t = id - 49152; int k = t >> 7, c = t & 127;
        woT[c * 128 + k] = f2bf(wo[t]);
    } else if (id < 131072) {
        int t = id - 65536; int k = t >> 9, c = t & 511;
        w1T[c * 128 + k] = f2bf(w1[t]);
    } else if (id < 196608) {
        int t = id - 131072; int k = t >> 7, c = t & 127;
        w2T[c * 512 + k] = f2bf(w2[t]);
    }
    if (id < 128) {
        bqkv[id] = bq[id];
        bqkv[128 + id] = bk[id];
        bqkv[256 + id] = bv[id];
    }
}

// ---------------------------------------------------------------------------
// Fragment loader for one k-step (32 cols): 4 A frags + 4 B frags.
// ---------------------------------------------------------------------------
template<int KT, bool IN_BF16>
__device__ __forceinline__ void ld_ab(bh8 (&av)[4], bh8 (&bv)[4],
                                      const float* __restrict__ Xf, const short* __restrict__ Xb,
                                      const int (&rowA)[4], const short* __restrict__ Wt,
                                      int C0, int l15, int kbase) {
#pragma unroll
    for (int rf = 0; rf < 4; ++rf) {
        if constexpr (IN_BF16) {
            av[rf] = *(const bh8*)(Xb + (size_t)rowA[rf] * KT + kbase);
        } else {
            f4 lo = *(const f4*)(Xf + (size_t)rowA[rf] * KT + kbase);
            f4 hi = *(const f4*)(Xf + (size_t)rowA[rf] * KT + kbase + 4);
            bh8 t;
            t[0] = f2bf(lo[0]); t[1] = f2bf(lo[1]); t[2] = f2bf(lo[2]); t[3] = f2bf(lo[3]);
            t[4] = f2bf(hi[0]); t[5] = f2bf(hi[1]); t[6] = f2bf(hi[2]); t[7] = f2bf(hi[3]);
            av[rf] = t;
        }
    }
#pragma unroll
    for (int cf = 0; cf < 4; ++cf)
        bv[cf] = *(const bh8*)(Wt + (size_t)(C0 + cf * 16 + l15) * KT + kbase);
}

__device__ __forceinline__ void mm16(f4 (&acc)[4][4], const bh8 (&av)[4], const bh8 (&bv)[4]) {
#pragma unroll
    for (int rf = 0; rf < 4; ++rf)
#pragma unroll
        for (int cf = 0; cf < 4; ++cf)
            acc[rf][cf] = __builtin_amdgcn_mfma_f32_16x16x32_bf16(av[rf], bv[cf], acc[rf][cf], 0, 0, 0);
}

// ---------------------------------------------------------------------------
// MFMA GEMM (qkv / wo): 256 threads = 2x2 waves; 128x128 per block.
// 2-deep ping-pong K-pipeline. XCD-aware panel placement.
// PLACE: grid-union fusion with INTERLEAVED dispatch — for blockIdx < 2*P,
// even blocks run the edge scatter, odd run GEMM; so scatter blocks are
// co-resident with GEMM blocks from t=0 (round 22's trailing layout only
// overlapped the tail). Requires P <= gemmBlocks.
// ---------------------------------------------------------------------------
#define CSTRIDE 136   // shorts; 272B row stride: 16B-aligned, breaks kg bank aliasing

template<int KT, bool IN_BF16, bool GELU, bool OUT_BF16, bool RESID, bool RBF16, bool STATS, bool PLACE>
__global__ __launch_bounds__(256, 2) void mfma_gemm(
    const void* __restrict__ Xv, const short* __restrict__ Wt, const float* __restrict__ bias,
    const void* __restrict__ resid,
    void* __restrict__ outv, float* __restrict__ slots, int n, int OC, int ncolb, int nrb,
    const int* __restrict__ edge, int* __restrict__ offw, int* __restrict__ sortedB,
    int E, int placeBlocks)
{
    int gemmIdx;
    if constexpr (PLACE) {
        const int P = placeBlocks;
        if ((int)blockIdx.x < 2 * P) {
            if ((blockIdx.x & 1) == 0) {
                // place role (even blocks of the interleaved prefix)
                int p = blockIdx.x >> 1;
                int t0 = p * 256 + threadIdx.x;
                int stride = P * 256;
                for (int e = t0; e < E; e += stride) {
                    int a = edge[e];
                    int pos = atomicAdd(&offw[a], 1);
                    sortedB[pos] = edge[E + e];
                }
                return;
            }
            gemmIdx = blockIdx.x >> 1;
        } else {
            gemmIdx = blockIdx.x - P;
        }
    } else {
        gemmIdx = blockIdx.x;
    }
    int bx, by;
    if (ncolb == 1) {
        bx = gemmIdx; by = 0;
    } else {
        int q = gemmIdx >> 3;
        by = q % ncolb;
        bx = (q / ncolb) * 8 + (gemmIdx & 7);
        if (bx >= nrb) return;
    }
    const int lane = threadIdx.x & 63;
    const int w = threadIdx.x >> 6;
    const int wr = w >> 1, wc = w & 1;
    const int R0 = bx * 128 + wr * 64;
    const int C0 = by * 128 + wc * 64;
    const int l15 = lane & 15;
    const int kg = lane >> 4;

    const float* Xf = (const float*)Xv;
    const short* Xb = (const short*)Xv;

    int rowA[4];
#pragma unroll
    for (int rf = 0; rf < 4; ++rf) rowA[rf] = min(R0 + rf * 16 + l15, n - 1);

    f4 acc[4][4];
#pragma unroll
    for (int rf = 0; rf < 4; ++rf)
#pragma unroll
        for (int cf = 0; cf < 4; ++cf) acc[rf][cf] = 0.f;

    constexpr int NT = KT / 32;
    bh8 aA[4], bA[4], aB[4], bB[4];

    ld_ab<KT, IN_BF16>(aA, bA, Xf, Xb, rowA, Wt, C0, l15, kg * 8);
#pragma unroll
    for (int t = 0; t < NT; t += 2) {
        ld_ab<KT, IN_BF16>(aB, bB, Xf, Xb, rowA, Wt, C0, l15, (t + 1) * 32 + kg * 8);
        mm16(acc, aA, bA);
        if (t + 2 < NT)
            ld_ab<KT, IN_BF16>(aA, bA, Xf, Xb, rowA, Wt, C0, l15, (t + 2) * 32 + kg * 8);
        mm16(acc, aB, bB);
    }

    if constexpr (OUT_BF16) {
        extern __shared__ short cs[];
        const int lrb = wr * 64;
        const int lcb = wc * 64;
#pragma unroll
        for (int cf = 0; cf < 4; ++cf) {
            const float bcol = bias[C0 + cf * 16 + l15];
#pragma unroll
            for (int rf = 0; rf < 4; ++rf) {
#pragma unroll
                for (int i = 0; i < 4; ++i) {
                    float val = acc[rf][cf][i] + bcol;
                    if constexpr (GELU) val = gelu_fast(val);
                    cs[(lrb + rf * 16 + kg * 4 + i) * CSTRIDE + lcb + cf * 16 + l15] = f2bf(val);
                }
            }
        }
        __syncthreads();
        const int tc = threadIdx.x & 15;
        const int tr = threadIdx.x >> 4;
        const int gcb = by * 128;
#pragma unroll
        for (int r = 0; r < 8; ++r) {
            int lrow = tr + r * 16;
            int grow = bx * 128 + lrow;
            if (grow < n) {
                bh8 v = *(bh8*)(cs + lrow * CSTRIDE + tc * 8);
                *(bh8*)((short*)outv + (size_t)grow * OC + gcb + tc * 8) = v;
            }
        }
    } else {
#pragma unroll
        for (int cf = 0; cf < 4; ++cf) {
            const int col = C0 + cf * 16 + l15;
            const float bcol = bias[col];
#pragma unroll
            for (int rf = 0; rf < 4; ++rf) {
                float s = 0.f, q = 0.f;
#pragma unroll
                for (int i = 0; i < 4; ++i) {
                    const int row = R0 + rf * 16 + kg * 4 + i;
                    if (row < n) {
                        float val = acc[rf][cf][i] + bcol;
                        if constexpr (RESID) {
                            float rv;
                            if constexpr (RBF16)
                                rv = bfbits2f((unsigned short)((const short*)resid)[(size_t)row * EMB + col]);
                            else
                                rv = ((const float*)resid)[(size_t)row * EMB + col];
                            val += rv;
                        }
                        if constexpr (GELU) val = gelu_fast(val);
                        if constexpr (STATS) { s += val; q += val * val; }
                        ((float*)outv)[(size_t)row * OC + col] = val;
                    }
                }
                if constexpr (STATS) {
                    s += __shfl_xor(s, 16, 64); s += __shfl_xor(s, 32, 64);
                    q += __shfl_xor(q, 16, 64); q += __shfl_xor(q, 32, 64);
                    if (kg == 0) {
                        float* sl = slots + (size_t)(bx & 63) * 256;
                        unsafeAtomicAdd(&sl[col], s);
                        unsafeAtomicAdd(&sl[128 + col], q);
                    }
                }
            }
        }
    }
}

// ---------------------------------------------------------------------------
// FUSED FFN (round-16 structure, best of 4 variants) + BN1-apply folded in:
// y2 = gelu(bn1(y1)@w1+b1)@w2 + b2 + bn1(y1), fused BN2 stats.
// ---------------------------------------------------------------------------
__global__ __launch_bounds__(256, 2) void ffn_fused(
    const float* __restrict__ y1, const float* __restrict__ scsh1,
    const short* __restrict__ w1T, const float* __restrict__ b1,
    const short* __restrict__ w2T, const float* __restrict__ b2,
    float* __restrict__ y2, float* __restrict__ slots, int n)
{
    extern __shared__ short hs[];   // [128][CSTRIDE] bf16
    const int bx = blockIdx.x;
    const int lane = threadIdx.x & 63;
    const int w = threadIdx.x >> 6;
    const int wr = w >> 1, wc = w & 1;
    const int R0 = bx * 128 + wr * 64;
    const int l15 = lane & 15;
    const int kg = lane >> 4;

    int rowA[4];
#pragma unroll
    for (int rf = 0; rf < 4; ++rf) rowA[rf] = min(R0 + rf * 16 + l15, n - 1);

    // hoisted bn1(y1) A-fragments (in-reg BN apply + bf16 convert)
    bh8 aF0[4], aF1[4], aF2[4], aF3[4];
#pragma unroll
    for (int seg = 0; seg < 4; ++seg) {
        const int kb = seg * 32 + kg * 8;
        f4 s0 = *(const f4*)(scsh1 + kb);
        f4 s1 = *(const f4*)(scsh1 + kb + 4);
        f4 h0 = *(const f4*)(scsh1 + 128 + kb);
        f4 h1 = *(const f4*)(scsh1 + 128 + kb + 4);
#pragma unroll
        for (int rf = 0; rf < 4; ++rf) {
            const float* p = y1 + (size_t)rowA[rf] * EMB + kb;
            f4 lo = *(const f4*)(p);
            f4 hi = *(const f4*)(p + 4);
            lo = lo * s0 + h0;
            hi = hi * s1 + h1;
            bh8 t;
            t[0] = f2bf(lo[0]); t[1] = f2bf(lo[1]); t[2] = f2bf(lo[2]); t[3] = f2bf(lo[3]);
            t[4] = f2bf(hi[0]); t[5] = f2bf(hi[1]); t[6] = f2bf(hi[2]); t[7] = f2bf(hi[3]);
            if (seg == 0) aF0[rf] = t;
            else if (seg == 1) aF1[rf] = t;
            else if (seg == 2) aF2[rf] = t;
            else aF3[rf] = t;
        }
    }

    f4 acc2[4][4];
#pragma unroll
    for (int rf = 0; rf < 4; ++rf)
#pragma unroll
        for (int cf = 0; cf < 4; ++cf) acc2[rf][cf] = 0.f;

    const int lrb = wr * 64;
    const int lcb = wc * 64;

    for (int c = 0; c < 4; ++c) {
        // ---- FC1 chunk: acc1 = bn1(y1) @ w1T[cols c*128+wc*64 .. +63] ----
        f4 acc1[4][4];
#pragma unroll
        for (int rf = 0; rf < 4; ++rf)
#pragma unroll
            for (int cf = 0; cf < 4; ++cf) acc1[rf][cf] = 0.f;

        bh8 bP[4], bQ[4];
        auto ldB1 = [&](bh8 (&dst)[4], int ks) {
#pragma unroll
            for (int cf = 0; cf < 4; ++cf) {
                int col = c * 128 + wc * 64 + cf * 16 + l15;
                dst[cf] = *(const bh8*)(w1T + (size_t)col * EMB + ks * 32 + kg * 8);
            }
        };
        ldB1(bP, 0);
        ldB1(bQ, 1);
        mm16(acc1, aF0, bP);
        ldB1(bP, 2);
        mm16(acc1, aF1, bQ);
        ldB1(bQ, 3);
        mm16(acc1, aF2, bP);
        mm16(acc1, aF3, bQ);

        // ---- fast GELU -> LDS tile ----
        __syncthreads();   // protect previous chunk's LDS reads
#pragma unroll
        for (int cf = 0; cf < 4; ++cf) {
            const float bcol = b1[c * 128 + wc * 64 + cf * 16 + l15];
#pragma unroll
            for (int rf = 0; rf < 4; ++rf) {
#pragma unroll
                for (int i = 0; i < 4; ++i) {
                    float val = gelu_fast(acc1[rf][cf][i] + bcol);
                    hs[(lrb + rf * 16 + kg * 4 + i) * CSTRIDE + lcb + cf * 16 + l15] = f2bf(val);
                }
            }
        }
        __syncthreads();

        // ---- FC2 partial: acc2 += h_chunk @ w2T[:, c*128..] ----
        bh8 aP[4], aQ[4];
        auto ldA2 = [&](bh8 (&dst)[4], int ks) {
#pragma unroll
            for (int rf = 0; rf < 4; ++rf)
                dst[rf] = *(const bh8*)(hs + (wr * 64 + rf * 16 + l15) * CSTRIDE + ks * 32 + kg * 8);
        };
        auto ldB2 = [&](bh8 (&dst)[4], int ks) {
#pragma unroll
            for (int cf = 0; cf < 4; ++cf) {
                int col = wc * 64 + cf * 16 + l15;
                dst[cf] = *(const bh8*)(w2T + (size_t)col * HID + c * 128 + ks * 32 + kg * 8);
            }
        };
        ldA2(aP, 0); ldB2(bP, 0);
        ldA2(aQ, 1); ldB2(bQ, 1);
        mm16(acc2, aP, bP);
        ldA2(aP, 2); ldB2(bP, 2);
        mm16(acc2, aQ, bQ);
        ldA2(aQ, 3); ldB2(bQ, 3);
        mm16(acc2, aP, bP);
        mm16(acc2, aQ, bQ);
    }

    // ---- epilogue: y2 = acc2 + b2 + bn1(y1) (fp32 resid), fused BN2 stats ----
    const int C0 = wc * 64;
#pragma unroll
    for (int cf = 0; cf < 4; ++cf) {
        const int col = C0 + cf * 16 + l15;
        const float bcol = b2[col];
        const float scv = scsh1[col];
        const float shv = scsh1[128 + col];
#pragma unroll
        for (int rf = 0; rf < 4; ++rf) {
            float s = 0.f, q = 0.f;
#pragma unroll
            for (int i = 0; i < 4; ++i) {
                const int row = R0 + rf * 16 + kg * 4 + i;
                if (row < n) {
                    float val = acc2[rf][cf][i] + bcol;
                    val += y1[(size_t)row * EMB + col] * scv + shv;
                    s += val; q += val * val;
                    y2[(size_t)row * EMB + col] = val;
                }
            }
            s += __shfl_xor(s, 16, 64); s += __shfl_xor(s, 32, 64);
            q += __shfl_xor(q, 16, 64); q += __shfl_xor(q, 32, 64);
            if (kg == 0) {
                float* sl = slots + (size_t)(bx & 63) * 256;
                unsafeAtomicAdd(&sl[col], s);
                unsafeAtomicAdd(&sl[128 + col], q);
            }
        }
    }
}

// ---------------------------------------------------------------------------
// FUSED gather+attention (round-14 vector-load version).
// ---------------------------------------------------------------------------
__global__ void gather_attn_kernel(const short* __restrict__ qkv, const int* __restrict__ off,
                                   const unsigned* __restrict__ cnt, const int* __restrict__ sortedB,
                                   const float* __restrict__ cntf, short* __restrict__ attno, int n) {
    int wid = (int)((blockIdx.x * blockDim.x + threadIdx.x) >> 6);
    int lane = threadIdx.x & 63;
    int nw = (gridDim.x * blockDim.x) >> 6;
    const int l15 = lane & 15;
    const int grp = lane >> 4;
    const int h = lane >> 3, g = lane & 7;
    for (int node = wid; node < n; node += nw) {
        int start = off[node];
        int deg = (int)cnt[node];
        float a[8];
#pragma unroll
        for (int i = 0; i < 8; ++i) a[i] = 0.f;
        for (int j = 0; j < deg; j += 8) {
            int i0 = j + grp, i1 = j + 4 + grp;
            uint4 u0 = make_uint4(0, 0, 0, 0), u1 = make_uint4(0, 0, 0, 0);
            if (i0 < deg) {
                int b = sortedB[start + i0];
                u0 = *(const uint4*)(qkv + (size_t)b * 384 + 128 + l15 * 8);
            }
            if (i1 < deg) {
                int b = sortedB[start + i1];
                u1 = *(const uint4*)(qkv + (size_t)b * 384 + 128 + l15 * 8);
            }
            unsigned w0[4] = {u0.x, u0.y, u0.z, u0.w};
            unsigned w1[4] = {u1.x, u1.y, u1.z, u1.w};
#pragma unroll
            for (int i = 0; i < 4; ++i) {
                a[2 * i]     += bfbits2f(w0[i] & 0xffffu) + bfbits2f(w1[i] & 0xffffu);
                a[2 * i + 1] += bfbits2f(w0[i] >> 16)     + bfbits2f(w1[i] >> 16);
            }
        }
#pragma unroll
        for (int i = 0; i < 8; ++i) {
            a[i] += __shfl_xor(a[i], 16, 64);
            a[i] += __shfl_xor(a[i], 32, 64);
        }

        const short* qp = qkv + (size_t)node * 384 + h * 16;
        uint4 qa = *(const uint4*)qp;
        uint4 qb = *(const uint4*)(qp + 8);
        float qv[16];
        {
            unsigned ua[4] = {qa.x, qa.y, qa.z, qa.w};
            unsigned ub[4] = {qb.x, qb.y, qb.z, qb.w};
#pragma unroll
            for (int w2 = 0; w2 < 4; ++w2) {
                qv[2 * w2]         = bfbits2f(ua[w2] & 0xffffu);
                qv[2 * w2 + 1]     = bfbits2f(ua[w2] >> 16);
                qv[8 + 2 * w2]     = bfbits2f(ub[w2] & 0xffffu);
                qv[8 + 2 * w2 + 1] = bfbits2f(ub[w2] >> 16);
            }
        }
        float s = 0.f;
#pragma unroll
        for (int i = 0; i < 8; ++i) {
            s += qv[i]     * __shfl(a[i], 2 * g, 64);
            s += qv[8 + i] * __shfl(a[i], 2 * g + 1, 64);
        }
        float c = cntf[node];
        s *= 1.0f / fmaxf(c, 1.0f);
        float m = s;
#pragma unroll
        for (int o = 1; o < 8; o <<= 1) m = fmaxf(m, __shfl_xor(m, o, 64));
        float e = __expf(s - m);
        float sum = e;
#pragma unroll
        for (int o = 1; o < 8; o <<= 1) sum += __shfl_xor(sum, o, 64);
        float p = e / sum;
        float o0 = 0.f, o1 = 0.f;
        int d0 = g * 2;
#pragma unroll
        for (int gg = 0; gg < 8; ++gg) {
            float pg = __shfl(p, h * 8 + gg, 64);
            unsigned vv = *(const unsigned*)(qkv + (size_t)node * 384 + 256 + gg * 16 + d0);
            o0 += pg * bfbits2f(vv & 0xffffu);
            o1 += pg * bfbits2f(vv >> 16);
        }
        unsigned pk = (unsigned)(unsigned short)f2bf(o0) | ((unsigned)(unsigned short)f2bf(o1) << 16);
        *(unsigned*)(attno + (size_t)node * EMB + h * 16 + d0) = pk;
    }
}

// ---------------------------------------------------------------------------
// BatchNorm helpers
// ---------------------------------------------------------------------------
__global__ void bn_finalize_slots(const float* __restrict__ slots, float* __restrict__ scsh,
                                  const float* __restrict__ g, const float* __restrict__ be, int n) {
    int c = threadIdx.x;
    float s = 0.f, q = 0.f;
    for (int i = 0; i < 64; ++i) {
        s += slots[(size_t)i * 256 + c];
        q += slots[(size_t)i * 256 + 128 + c];
    }
    float invn = 1.0f / (float)n;
    float mean = s * invn;
    float var = fmaxf(q * invn - mean * mean, 0.f);
    float sc = g[c] * rsqrtf(var + 1e-5f);
    scsh[c] = sc;
    scsh[128 + c] = be[c] - mean * sc;
}

// BN2 finalize + apply MERGED: each block redundantly reduces the 64 stat
// slot groups (L2-hot, ~64KB) into LDS scale/shift, then applies to Y.
__global__ void bn_final_apply(const float* __restrict__ slots,
                               const float* __restrict__ g, const float* __restrict__ be,
                               float* __restrict__ Y, int n) {
    __shared__ float sc[128], sh[128];
    int tid = threadIdx.x;
    if (tid < 128) {
        float s = 0.f, q = 0.f;
        for (int i = 0; i < 64; ++i) {
            s += slots[(size_t)i * 256 + tid];
            q += slots[(size_t)i * 256 + 128 + tid];
        }
        float invn = 1.0f / (float)n;
        float mean = s * invn;
        float var = fmaxf(q * invn - mean * mean, 0.f);
        float scv = g[tid] * rsqrtf(var + 1e-5f);
        sc[tid] = scv;
        sh[tid] = be[tid] - mean * scv;
    }
    __syncthreads();
    size_t total4 = (size_t)n * EMB / 4;
    size_t stride = (size_t)gridDim.x * blockDim.x;
    for (size_t i = (size_t)blockIdx.x * blockDim.x + tid; i < total4; i += stride) {
        f4 vv = ((f4*)Y)[i];
        int c = (int)((i * 4) & 127);
#pragma unroll
        for (int j = 0; j < 4; ++j) vv[j] = vv[j] * sc[c + j] + sh[c + j];
        ((f4*)Y)[i] = vv;
    }
}

// ---------------------------------------------------------------------------
extern "C" void kernel_launch(void* const* d_in, const int* in_sizes, int n_in,
                              void* d_out, int out_size, void* d_ws, size_t ws_size,
                              hipStream_t stream) {
    const float* x   = (const float*)d_in[0];
    const float* wq  = (const float*)d_in[1];
    const float* bq  = (const float*)d_in[2];
    const float* wk  = (const float*)d_in[3];
    const float* bk  = (const float*)d_in[4];
    const float* wv  = (const float*)d_in[5];
    const float* bv  = (const float*)d_in[6];
    const float* wo  = (const float*)d_in[7];
    const float* bo  = (const float*)d_in[8];
    const float* w1  = (const float*)d_in[9];
    const float* b1  = (const float*)d_in[10];
    const float* w2  = (const float*)d_in[11];
    const float* b2  = (const float*)d_in[12];
    const float* g1  = (const float*)d_in[13];
    const float* be1 = (const float*)d_in[14];
    const float* g2  = (const float*)d_in[15];
    const float* be2 = (const float*)d_in[16];
    const int* edge  = (const int*)d_in[17];

    int n = in_sizes[0] / EMB;      // 50000
    int E = in_sizes[17] / 2;       // 800000

    // workspace layout (float units)
    float* wsf = (float*)d_ws;
    unsigned* cnt_u = (unsigned*)wsf;                       // 65536
    float*  cntf  = wsf + 65536;                            // 65536
    int*    off   = (int*)(wsf + 2 * 65536);                // 65536
    int*    offw  = (int*)(wsf + 3 * 65536);                // 65536
    int*    bsum  = (int*)(wsf + 4 * 65536);                // 64
    int*    sortedB = (int*)(wsf + 4 * 65536 + 64);         // E
    float*  base5 = wsf + 4 * 65536 + 64 + E;
    short*  qkv   = (short*)base5;                          // n*384 bf16 = n*192 f
    short*  attno = (short*)(base5 + (size_t)n * 256);      // n*128 bf16
    float*  y1    = base5 + (size_t)n * 320;                // n*128 f
    float*  warea = y1 + (size_t)n * 128;
    short*  wqkvT = (short*)warea;                          // 384*128 bf16
    short*  woT   = wqkvT + 384 * 128;                      // 128*128
    short*  w1T   = woT + 128 * 128;                        // 512*128
    short*  w2T   = w1T + 512 * 128;                        // 128*512
    float*  bqkv  = (float*)(w2T + 128 * 512);              // 384
    float*  slots1 = bqkv + 384;                            // 64*256
    float*  slots2 = slots1 + 64 * 256;                     // 64*256
    float*  scsh1  = slots2 + 64 * 256;                     // 256
    float*  y2    = (float*)d_out;

    hipMemsetAsync(cnt_u, 0, 65536 * sizeof(unsigned), stream);
    hipMemsetAsync(slots1, 0, 2 * 64 * 256 * sizeof(float), stream);

    // weight prep FUSED with edge histogram (data-independent grid union)
    prep_all<<<768 + 1024, 256, 0, stream>>>(wq, wk, wv, wo, w1, w2, bq, bk, bv,
                                             wqkvT, woT, w1T, w2T, bqkv,
                                             edge, cnt_u, E, 768);

    // scan chain
    int nb = (n + 1023) / 1024;  // 49
    scan_blocks<<<nb, 256, 0, stream>>>(cnt_u, off, bsum, n);
    scan_bsums<<<1, 64, 0, stream>>>(bsum, nb);
    scan_apply<<<nb, 256, 0, stream>>>(cnt_u, bsum, off, offw, cntf, n);

    int nrb = (n + 127) / 128;              // 391 row-groups
    int nrb8 = ((nrb + 7) / 8) * 8;         // 392, XCD-aligned
    const size_t CSH = 128 * CSTRIDE * sizeof(short);  // 34816 B
    const int PLACE_BLK = 1024;             // must be <= nrb8*3

    // qkv = x @ [wq|wk|wv] + bqkv (bf16 out [n][384]) FUSED with edge placement
    // (interleaved roles: even prefix blocks scatter, odd run GEMM)
    mfma_gemm<128, false, false, true, false, false, false, true>
        <<<nrb8 * 3 + PLACE_BLK, 256, CSH, stream>>>(
        x, wqkvT, bqkv, nullptr, qkv, nullptr, n, 384, 3, nrb,
        edge, offw, sortedB, E, PLACE_BLK);

    // fused: ksum gather (in regs, vector loads) + attention -> attno
    gather_attn_kernel<<<6144, 256, 0, stream>>>(qkv, off, cnt_u, sortedB, cntf, attno, n);

    // y1 = attno@wo + bo + x (fp32 out) + fused BN1 stats
    mfma_gemm<128, true, false, false, true, false, true, false><<<nrb, 256, 0, stream>>>(
        attno, woT, bo, x, y1, slots1, n, EMB, 1, nrb,
        nullptr, nullptr, nullptr, 0, 0);

    bn_finalize_slots<<<1, 128, 0, stream>>>(slots1, scsh1, g1, be1, n);

    // FUSED FFN (BN1-apply folded in): y2 = gelu(bn1(y1)@w1+b1)@w2 + b2 + bn1(y1)
    ffn_fused<<<nrb, 256, CSH, stream>>>(y1, scsh1, w1T, b1, w2T, b2, y2, slots2, n);

    // BN2 finalize + apply merged (per-block redundant slot reduce)
    bn_final_apply<<<512, 256, 0, stream>>>(slots2, g2, be2, y2, n);
}